// Round 2
// baseline (44995.328 us; speedup 1.0000x reference)
//
#include <hip/hip_runtime.h>

// ============================================================================
// ImprovedMoE fp32. R2: conv trunk rewritten — shuffle x-halo, LDS weights
// (broadcast ds_read_b128, no SMEM in inner loop), double-buffered chunks
// with one barrier/chunk, shuffle avgpool, 2-image blocks for 8x8 convs.
// ============================================================================

__global__ void wt_transpose_k(const float* __restrict__ w, float* __restrict__ wt,
                               int CI9, int CO) {
  int n = CI9 * CO;
  int idx = blockIdx.x * 256 + threadIdx.x;
  if (idx < n) {
    int co = idx % CO;
    int r  = idx / CO;            // r = ci*9 + tap
    wt[idx] = w[(size_t)co * CI9 + r];
  }
}

// ---------------------------------------------------------------------------
// Direct 3x3 SAME conv + bias + BN + ReLU, optional fused pool.
// POOL: 0 none, 1 2x2 maxpool, 2 global avg -> feats.
// Lane tiling: LPR = W/PX lanes per row, WR = 64/LPR rows per wave.
// B_PER images per block (for 8x8 convs). Wave w owns co range [co0, co0+CO_W).
// LDS: sIn[2][B_PER][CC][WR+2][W+4] (no x-halo; halo via shfl),
//      sW [2][CC*9][BLOCK_CO+4]  (broadcast reads).
// ---------------------------------------------------------------------------
template<int H, int W, int CIN, int COUT, int CO_W, int PX, int CC, int POOL, int B_PER>
__global__ __launch_bounds__(256, 4) void conv3x3(
    const float* __restrict__ in, const float* __restrict__ wt,
    const float* __restrict__ cb, const float* __restrict__ bns,
    const float* __restrict__ bnb, float* __restrict__ out)
{
  constexpr int LPR = W / PX;
  constexpr int WR  = 64 / LPR;
  constexpr int RS  = W + 4;                  // padded LDS row stride
  constexpr int BLOCK_CO = 4 * CO_W;
  constexpr int WS  = BLOCK_CO + 4;           // padded weight row stride
  constexpr int NC  = CIN / CC;
  constexpr int W4  = W / 4;
  constexpr int SI4 = B_PER * CC * (WR + 2) * W4;   // input float4s per chunk
  constexpr int SW4 = CC * 9 * (BLOCK_CO / 4);      // weight float4s per chunk
  constexpr int NI  = (SI4 + 255) / 256;
  constexpr int NW  = (SW4 + 255) / 256;
  constexpr int IMG_STRIDE = CC * (WR + 2) * RS;

  __shared__ float sIn[2][B_PER * CC * (WR + 2) * RS];
  __shared__ float sW [2][CC * 9 * WS];

  const int tid  = threadIdx.x;
  const int lane = tid & 63;
  const int wave = tid >> 6;
  const int bx   = blockIdx.x;
  const int coB  = blockIdx.y * BLOCK_CO;
  const int co0  = coB + wave * CO_W;
  const int r0   = blockIdx.z * WR;
  const int row  = lane / LPR;
  const int xi   = lane % LPR;
  const int x0   = xi * PX;

  float acc[B_PER][PX][CO_W];
#pragma unroll
  for (int g = 0; g < B_PER; ++g)
#pragma unroll
    for (int p = 0; p < PX; ++p)
#pragma unroll
      for (int j = 0; j < CO_W; ++j) acc[g][p][j] = 0.f;

  float4 ri[NI], rw[NW];

  auto stage_load = [&](int k) {
    const int c0 = k * CC;
#pragma unroll
    for (int i = 0; i < NI; ++i) {
      int id = tid + i * 256;
      float4 v = make_float4(0.f, 0.f, 0.f, 0.f);
      if (SI4 % 256 == 0 || id < SI4) {
        int img = (B_PER == 1) ? 0 : id / (CC * (WR + 2) * W4);
        int rem = (B_PER == 1) ? id : id % (CC * (WR + 2) * W4);
        int c   = rem / ((WR + 2) * W4);
        int r2  = rem % ((WR + 2) * W4);
        int rr  = r2 / W4;
        int seg = r2 % W4;
        int gr  = r0 + rr - 1;
        if (gr >= 0 && gr < H)
          v = *(const float4*)&in[(((size_t)(bx * B_PER + img) * CIN + c0 + c) * H + gr) * W + seg * 4];
      }
      ri[i] = v;
    }
#pragma unroll
    for (int i = 0; i < NW; ++i) {
      int id = tid + i * 256;
      if (SW4 % 256 == 0 || id < SW4) {
        int rl  = id / (BLOCK_CO / 4);
        int seg = id % (BLOCK_CO / 4);
        rw[i] = *(const float4*)&wt[((size_t)c0 * 9 + rl) * COUT + coB + seg * 4];
      }
    }
  };

  auto stage_store = [&](int buf) {
#pragma unroll
    for (int i = 0; i < NI; ++i) {
      int id = tid + i * 256;
      if (SI4 % 256 == 0 || id < SI4) {
        int img = (B_PER == 1) ? 0 : id / (CC * (WR + 2) * W4);
        int rem = (B_PER == 1) ? id : id % (CC * (WR + 2) * W4);
        int c   = rem / ((WR + 2) * W4);
        int r2  = rem % ((WR + 2) * W4);
        int rr  = r2 / W4;
        int seg = r2 % W4;
        *(float4*)&sIn[buf][img * IMG_STRIDE + (c * (WR + 2) + rr) * RS + seg * 4] = ri[i];
      }
    }
#pragma unroll
    for (int i = 0; i < NW; ++i) {
      int id = tid + i * 256;
      if (SW4 % 256 == 0 || id < SW4) {
        int rl  = id / (BLOCK_CO / 4);
        int seg = id % (BLOCK_CO / 4);
        *(float4*)&sW[buf][rl * WS + seg * 4] = rw[i];
      }
    }
  };

  auto compute = [&](int buf) {
    const float* bI = sIn[buf];
    const float* bW = sW[buf];
#pragma unroll
    for (int c = 0; c < CC; ++c) {
      float r[B_PER][3][PX + 2];
#pragma unroll
      for (int img = 0; img < B_PER; ++img) {
#pragma unroll
        for (int dy = 0; dy < 3; ++dy) {
          const float* lp = &bI[img * IMG_STRIDE + (c * (WR + 2) + row + dy) * RS + x0];
          if constexpr (PX == 8) {
            float4 a = *(const float4*)lp;
            float4 b = *(const float4*)(lp + 4);
            r[img][dy][1] = a.x; r[img][dy][2] = a.y; r[img][dy][3] = a.z; r[img][dy][4] = a.w;
            r[img][dy][5] = b.x; r[img][dy][6] = b.y; r[img][dy][7] = b.z; r[img][dy][8] = b.w;
          } else if constexpr (PX == 4) {
            float4 a = *(const float4*)lp;
            r[img][dy][1] = a.x; r[img][dy][2] = a.y; r[img][dy][3] = a.z; r[img][dy][4] = a.w;
          } else {
            r[img][dy][1] = lp[0];
          }
          float lv = __shfl_up(r[img][dy][PX], 1);
          float rv = __shfl_down(r[img][dy][1], 1);
          r[img][dy][0]      = (xi == 0)       ? 0.f : lv;
          r[img][dy][PX + 1] = (xi == LPR - 1) ? 0.f : rv;
        }
      }
#pragma unroll
      for (int t = 0; t < 9; ++t) {
        const int dy = t / 3, dx = t % 3;
        const float* wp = &bW[(c * 9 + t) * WS + wave * CO_W];
        float w[CO_W];
#pragma unroll
        for (int j4 = 0; j4 < CO_W; j4 += 4) {
          float4 wv = *(const float4*)&wp[j4];
          w[j4] = wv.x; w[j4 + 1] = wv.y; w[j4 + 2] = wv.z; w[j4 + 3] = wv.w;
        }
#pragma unroll
        for (int img = 0; img < B_PER; ++img)
#pragma unroll
          for (int p = 0; p < PX; ++p) {
            float iv = r[img][dy][p + dx];
#pragma unroll
            for (int j = 0; j < CO_W; ++j)
              acc[img][p][j] = fmaf(iv, w[j], acc[img][p][j]);
          }
      }
    }
  };

  stage_load(0);
  stage_store(0);
  __syncthreads();
#pragma unroll 1
  for (int k = 0; k < NC; ++k) {
    if (k + 1 < NC) stage_load(k + 1);
    compute(k & 1);
    if (k + 1 < NC) stage_store((k + 1) & 1);
    __syncthreads();
  }

  // ---- epilogue: y = conv*s + (cb*s+bb); relu; pool ----
  float es[CO_W], eb[CO_W];
#pragma unroll
  for (int j = 0; j < CO_W; ++j) {
    float s_ = bns[co0 + j];
    es[j] = s_;
    eb[j] = fmaf(cb[co0 + j], s_, bnb[co0 + j]);
  }

  if constexpr (POOL == 0) {
    const int r = r0 + row;
#pragma unroll
    for (int img = 0; img < B_PER; ++img)
#pragma unroll
      for (int j = 0; j < CO_W; ++j) {
        float* op = out + (((size_t)(bx * B_PER + img) * COUT + co0 + j) * H + r) * W + x0;
        if constexpr (PX == 8) {
#pragma unroll
          for (int p4 = 0; p4 < PX; p4 += 4) {
            float v0 = fmaxf(fmaf(acc[img][p4 + 0][j], es[j], eb[j]), 0.f);
            float v1 = fmaxf(fmaf(acc[img][p4 + 1][j], es[j], eb[j]), 0.f);
            float v2 = fmaxf(fmaf(acc[img][p4 + 2][j], es[j], eb[j]), 0.f);
            float v3 = fmaxf(fmaf(acc[img][p4 + 3][j], es[j], eb[j]), 0.f);
            *(float4*)(op + p4) = make_float4(v0, v1, v2, v3);
          }
        } else if constexpr (PX == 4) {
          float v0 = fmaxf(fmaf(acc[img][0][j], es[j], eb[j]), 0.f);
          float v1 = fmaxf(fmaf(acc[img][1][j], es[j], eb[j]), 0.f);
          float v2 = fmaxf(fmaf(acc[img][2][j], es[j], eb[j]), 0.f);
          float v3 = fmaxf(fmaf(acc[img][3][j], es[j], eb[j]), 0.f);
          *(float4*)op = make_float4(v0, v1, v2, v3);
        } else {
          op[0] = fmaxf(fmaf(acc[img][0][j], es[j], eb[j]), 0.f);
        }
      }
  } else if constexpr (POOL == 1) {   // PX==4 configs
    const int r = r0 + row;
#pragma unroll
    for (int j = 0; j < CO_W; ++j) {
      float v0 = fmaxf(fmaf(acc[0][0][j], es[j], eb[j]), 0.f);
      float v1 = fmaxf(fmaf(acc[0][1][j], es[j], eb[j]), 0.f);
      float v2 = fmaxf(fmaf(acc[0][2][j], es[j], eb[j]), 0.f);
      float v3 = fmaxf(fmaf(acc[0][3][j], es[j], eb[j]), 0.f);
      float m01 = fmaxf(v0, v1), m23 = fmaxf(v2, v3);
      float o01 = __shfl_xor(m01, LPR);
      float o23 = __shfl_xor(m23, LPR);
      float p0 = fmaxf(m01, o01), p1 = fmaxf(m23, o23);
      if ((row & 1) == 0) {
        float* op = out + (((size_t)bx * COUT + co0 + j) * (H / 2) + (r >> 1)) * (W / 2) + (x0 >> 1);
        *(float2*)op = make_float2(p0, p1);
      }
    }
  } else {  // POOL == 2: global avg over H*W=64 px (PX==1, lane==pixel), B_PER==2
    float myv = 0.f;
#pragma unroll
    for (int img = 0; img < B_PER; ++img)
#pragma unroll
      for (int j = 0; j < CO_W; ++j) {
        float v = fmaxf(fmaf(acc[img][0][j], es[j], eb[j]), 0.f);
#pragma unroll
        for (int s = 32; s >= 1; s >>= 1) v += __shfl_xor(v, s);
        if (lane == img * CO_W + j) myv = v * (1.f / 64.f);
      }
    if (lane < B_PER * CO_W) {
      int img = lane / CO_W, j = lane % CO_W;
      out[(size_t)(bx * B_PER + img) * COUT + co0 + j] = myv;
    }
  }
}

// ---------------------------------------------------------------------------
// Batched head GEMM (unchanged from R1, verified correct).
// ---------------------------------------------------------------------------
template<int O, int K, int LN, int RELU>
__global__ __launch_bounds__(256, 4) void gemm_head(
    const float* __restrict__ A, size_t aStrideE,
    const float* __restrict__ Wm, const float* __restrict__ bias,
    const float* __restrict__ g, const float* __restrict__ bb,
    float* __restrict__ out)
{
  constexpr int KC  = (O >= 256) ? 32 : 64;
  constexpr int WST = O + 4;
  constexpr int TO  = O / 16;
  __shared__ float sA[KC * 68];
  __shared__ float sW[KC * WST];
  __shared__ float mArr[64], rArr[64];

  const int tid  = threadIdx.x;
  const int lane = tid & 63;
  const int wave = tid >> 6;
  const int e    = blockIdx.y;
  const int b0g  = blockIdx.x * 64;
  const int bl   = (lane & 15) * 4;
  const int ol   = wave * (O / 4) + (lane >> 4) * TO;

  const float* Ae = A + (size_t)e * aStrideE;
  const float* We = Wm + (size_t)e * O * K;

  float acc[4][TO];
#pragma unroll
  for (int i = 0; i < 4; ++i)
#pragma unroll
    for (int j = 0; j < TO; ++j) acc[i][j] = 0.f;

  for (int k0 = 0; k0 < K; k0 += KC) {
    for (int idx = tid; idx < 64 * KC; idx += 256) {
      int kk = idx % KC, bb_ = idx / KC;
      sA[kk * 68 + bb_] = Ae[(size_t)(b0g + bb_) * K + k0 + kk];
    }
    for (int idx = tid; idx < O * KC; idx += 256) {
      int kk = idx % KC, oo = idx / KC;
      sW[kk * WST + oo] = We[(size_t)oo * K + k0 + kk];
    }
    __syncthreads();
#pragma unroll 4
    for (int kk = 0; kk < KC; ++kk) {
      float4 av = *(const float4*)&sA[kk * 68 + bl];
      float a4[4] = {av.x, av.y, av.z, av.w};
#pragma unroll
      for (int j4 = 0; j4 < TO; j4 += 4) {
        float4 wv = *(const float4*)&sW[kk * WST + ol + j4];
        float w4[4] = {wv.x, wv.y, wv.z, wv.w};
#pragma unroll
        for (int i = 0; i < 4; ++i)
#pragma unroll
          for (int jj = 0; jj < 4; ++jj)
            acc[i][j4 + jj] = fmaf(a4[i], w4[jj], acc[i][j4 + jj]);
      }
    }
    __syncthreads();
  }

  const float* bi = bias + (size_t)e * O;
#pragma unroll
  for (int i = 0; i < 4; ++i)
#pragma unroll
    for (int j = 0; j < TO; ++j) acc[i][j] += bi[ol + j];

  if constexpr (LN) {
    float* redS = sA;
    float* redQ = sA + 1024;
    const int grp = wave * 4 + (lane >> 4);
#pragma unroll
    for (int i = 0; i < 4; ++i) {
      float s = 0.f, q = 0.f;
#pragma unroll
      for (int j = 0; j < TO; ++j) { s += acc[i][j]; q += acc[i][j] * acc[i][j]; }
      redS[(bl + i) * 16 + grp] = s;
      redQ[(bl + i) * 16 + grp] = q;
    }
    __syncthreads();
    if (tid < 64) {
      float s = 0.f, q = 0.f;
#pragma unroll
      for (int gi = 0; gi < 16; ++gi) { s += redS[tid * 16 + gi]; q += redQ[tid * 16 + gi]; }
      float mean = s * (1.f / O);
      float var  = q * (1.f / O) - mean * mean;
      mArr[tid] = mean;
      rArr[tid] = rsqrtf(var + 1e-5f);
    }
    __syncthreads();
    const float* gp  = g + (size_t)e * O;
    const float* bbp = bb + (size_t)e * O;
#pragma unroll
    for (int i = 0; i < 4; ++i) {
      float mean = mArr[bl + i], rstd = rArr[bl + i];
#pragma unroll
      for (int j = 0; j < TO; ++j)
        acc[i][j] = (acc[i][j] - mean) * rstd * gp[ol + j] + bbp[ol + j];
    }
  }
  if constexpr (RELU) {
#pragma unroll
    for (int i = 0; i < 4; ++i)
#pragma unroll
      for (int j = 0; j < TO; ++j) acc[i][j] = fmaxf(acc[i][j], 0.f);
  }
#pragma unroll
  for (int i = 0; i < 4; ++i) {
    float* op = out + ((size_t)e * 512 + b0g + bl + i) * O + ol;
#pragma unroll
    for (int j4 = 0; j4 < TO; j4 += 4)
      *(float4*)(op + j4) = make_float4(acc[i][j4], acc[i][j4 + 1], acc[i][j4 + 2], acc[i][j4 + 3]);
  }
}

__global__ void cls_softmax_k(const float* __restrict__ embeds,
                              const float* __restrict__ cw,
                              const float* __restrict__ cbias,
                              float* __restrict__ logits_e,
                              float* __restrict__ conf)
{
  int wv   = (blockIdx.x * 256 + threadIdx.x) >> 6;
  int lane = threadIdx.x & 63;
  int b = wv >> 4, e = wv & 15;
  const float* ep = embeds + ((size_t)e * 512 + b) * 128;
  float e0 = ep[lane], e1 = ep[lane + 64];
  float l[10];
#pragma unroll
  for (int o = 0; o < 10; ++o) {
    const float* wp = cw + ((size_t)e * 10 + o) * 128;
    l[o] = e0 * wp[lane] + e1 * wp[lane + 64];
  }
#pragma unroll
  for (int s = 32; s >= 1; s >>= 1)
#pragma unroll
    for (int o = 0; o < 10; ++o) l[o] += __shfl_xor(l[o], s, 64);
#pragma unroll
  for (int o = 0; o < 10; ++o) l[o] += cbias[e * 10 + o];
  float m = l[0];
#pragma unroll
  for (int o = 1; o < 10; ++o) m = fmaxf(m, l[o]);
  float p[10], sum = 0.f;
#pragma unroll
  for (int o = 0; o < 10; ++o) { p[o] = expf(l[o] - m); sum += p[o]; }
  float inv = 1.f / sum, ent = 0.f;
#pragma unroll
  for (int o = 0; o < 10; ++o) { float pp = p[o] * inv; ent -= pp * logf(pp + 1e-12f); }
  if (lane == 0) {
    conf[b * 16 + e] = -ent;
#pragma unroll
    for (int o = 0; o < 10; ++o) logits_e[((size_t)b * 16 + e) * 10 + o] = l[o];
  }
}

__global__ void gate23_k(const float* __restrict__ g1, const float* __restrict__ w2,
                         const float* __restrict__ b2, const float* __restrict__ w3,
                         const float* __restrict__ b3, float* __restrict__ scores)
{
  int wv   = (blockIdx.x * 256 + threadIdx.x) >> 6;
  int lane = threadIdx.x & 63;
  int b = wv >> 4, e = wv & 15;
  float gv = g1[((size_t)e * 512 + b) * 64 + lane];
  const float* w3p = w3 + e * 32;
  float sc = 0.f;
#pragma unroll
  for (int o = 0; o < 32; ++o) {
    float t = gv * w2[((size_t)e * 32 + o) * 64 + lane];
#pragma unroll
    for (int s = 32; s >= 1; s >>= 1) t += __shfl_xor(t, s, 64);
    float g2v = fmaxf(t + b2[e * 32 + o], 0.f);
    sc = fmaf(g2v, w3p[o], sc);
  }
  if (lane == 0) scores[b * 16 + e] = sc + b3[e];   // RTEMP == 1
}

__global__ void routing_k(const float* __restrict__ scores, const float* __restrict__ conf,
                          const float* __restrict__ logits_e, float* __restrict__ out)
{
  __shared__ int t2[512];
  __shared__ int chs[512];
  const int tid = threadIdx.x;

  if (tid < 512) {
    int b = tid;
    float v0 = -3.4e38f, v1 = -3.4e38f;
    int i0 = 0, i1 = 0;
#pragma unroll
    for (int e = 0; e < 16; ++e) {
      float s = scores[b * 16 + e];
      float c = conf[b * 16 + e];
      float v = 0.7f * s + 0.3f * c - 0.125f;
      out[5120 + b * 16 + e] = v;   // balanced output
      if (v > v0) { v1 = v0; i1 = i0; v0 = v; i0 = e; }
      else if (v > v1) { v1 = v; i1 = e; }
    }
    t2[b] = i0 | (i1 << 8);
  }
  __syncthreads();

  if (tid < 64) {
    int lane = tid;
    int cnt = 0;
    int pk[8];
#pragma unroll
    for (int k = 0; k < 8; ++k) pk[k] = t2[k * 64 + lane];
#pragma unroll 1
    for (int k = 0; k < 8; ++k) {
      for (int j = 0; j < 64; ++j) {
        int pair = __shfl(pk[k], j, 64);
        int i0 = pair & 0xff, i1 = (pair >> 8) & 0xff;
        int c0 = __shfl(cnt, i0, 64);
        int c1 = __shfl(cnt, i1, 64);
        int ch = (c0 < 64) ? i0 : ((c1 < 64) ? i1 : ((c0 <= c1) ? i0 : i1));
        cnt += (lane == ch) ? 1 : 0;
        if (lane == 0) chs[k * 64 + j] = ch;
      }
    }
  }
  __syncthreads();

  if (tid < 512) {
    int b = tid;
    int ch = chs[b];
#pragma unroll
    for (int e = 0; e < 16; ++e)
      out[13312 + b * 16 + e] = (e == ch) ? 1.0f : 0.0f;   // D
#pragma unroll
    for (int o = 0; o < 10; ++o)
      out[b * 10 + o] = logits_e[((size_t)b * 16 + ch) * 10 + o];  // final_logits
  }
}

// ============================================================================
extern "C" void kernel_launch(void* const* d_in, const int* in_sizes, int n_in,
                              void* d_out, int out_size, void* d_ws, size_t ws_size,
                              hipStream_t stream) {
  (void)in_sizes; (void)n_in; (void)out_size; (void)ws_size;

  const float* x = (const float*)d_in[0];
  const float *cw[6], *cbv[6], *bsv[6], *bbv[6];
  for (int i = 0; i < 6; ++i) {
    cw[i]  = (const float*)d_in[1 + 4 * i];
    cbv[i] = (const float*)d_in[2 + 4 * i];
    bsv[i] = (const float*)d_in[3 + 4 * i];
    bbv[i] = (const float*)d_in[4 + 4 * i];
  }
  const float* gate_w1  = (const float*)d_in[25];
  const float* gate_b1  = (const float*)d_in[26];
  const float* gate_g1  = (const float*)d_in[27];
  const float* gate_bb1 = (const float*)d_in[28];
  const float* gate_w2  = (const float*)d_in[29];
  const float* gate_b2  = (const float*)d_in[30];
  const float* gate_w3  = (const float*)d_in[31];
  const float* gate_b3  = (const float*)d_in[32];
  const float* exp_w1   = (const float*)d_in[33];
  const float* exp_b1   = (const float*)d_in[34];
  const float* exp_g1   = (const float*)d_in[35];
  const float* exp_bb1  = (const float*)d_in[36];
  const float* exp_w2   = (const float*)d_in[37];
  const float* exp_b2   = (const float*)d_in[38];
  const float* exp_g2   = (const float*)d_in[39];
  const float* exp_bb2  = (const float*)d_in[40];
  const float* exp_w3   = (const float*)d_in[41];
  const float* exp_b3   = (const float*)d_in[42];
  const float* cls_w    = (const float*)d_in[43];
  const float* cls_b    = (const float*)d_in[44];

  float* ws = (float*)d_ws;
  size_t o_wt1 = 0;
  size_t o_wt2 = o_wt1 + 1728;
  size_t o_wt3 = o_wt2 + 36864;
  size_t o_wt4 = o_wt3 + 73728;
  size_t o_wt5 = o_wt4 + 147456;
  size_t o_wt6 = o_wt5 + 294912;
  size_t o_bufA  = o_wt6 + 589824;
  size_t o_bufB  = o_bufA + 33554432ull;
  size_t o_feats = o_bufB + 8388608ull;
  size_t o_h1    = o_feats + 131072;
  size_t o_h2    = o_h1 + 2097152;
  size_t o_emb   = o_h2 + 1048576;
  size_t o_g1    = o_emb + 1048576;
  size_t o_lg    = o_g1 + 524288;
  size_t o_conf  = o_lg + 81920;
  size_t o_sc    = o_conf + 8192;

  float* wt1 = ws + o_wt1; float* wt2 = ws + o_wt2; float* wt3 = ws + o_wt3;
  float* wt4 = ws + o_wt4; float* wt5 = ws + o_wt5; float* wt6 = ws + o_wt6;
  float* bufA = ws + o_bufA; float* bufB = ws + o_bufB;
  float* feats = ws + o_feats; float* h1 = ws + o_h1; float* h2 = ws + o_h2;
  float* emb = ws + o_emb; float* g1 = ws + o_g1; float* lg = ws + o_lg;
  float* conf = ws + o_conf; float* sc = ws + o_sc;

  auto cdiv = [](int a, int b) { return (a + b - 1) / b; };

  // ---- weight transposes ----
  wt_transpose_k<<<cdiv(27 * 64, 256), 256, 0, stream>>>(cw[0], wt1, 27, 64);
  wt_transpose_k<<<cdiv(576 * 64, 256), 256, 0, stream>>>(cw[1], wt2, 576, 64);
  wt_transpose_k<<<cdiv(576 * 128, 256), 256, 0, stream>>>(cw[2], wt3, 576, 128);
  wt_transpose_k<<<cdiv(1152 * 128, 256), 256, 0, stream>>>(cw[3], wt4, 1152, 128);
  wt_transpose_k<<<cdiv(1152 * 256, 256), 256, 0, stream>>>(cw[4], wt5, 1152, 256);
  wt_transpose_k<<<cdiv(2304 * 256, 256), 256, 0, stream>>>(cw[5], wt6, 2304, 256);

  // ---- trunk ----
  // <H, W, CIN, COUT, CO_W, PX, CC, POOL, B_PER>
  conv3x3<32, 32, 3, 64, 8, 4, 3, 0, 1><<<dim3(512, 2, 4), 256, 0, stream>>>(
      x, wt1, cbv[0], bsv[0], bbv[0], bufA);
  conv3x3<32, 32, 64, 64, 8, 4, 4, 1, 1><<<dim3(512, 2, 4), 256, 0, stream>>>(
      bufA, wt2, cbv[1], bsv[1], bbv[1], bufB);
  conv3x3<16, 16, 64, 128, 8, 4, 4, 0, 1><<<dim3(512, 4, 1), 256, 0, stream>>>(
      bufB, wt3, cbv[2], bsv[2], bbv[2], bufA);
  conv3x3<16, 16, 128, 128, 8, 4, 4, 1, 1><<<dim3(512, 4, 1), 256, 0, stream>>>(
      bufA, wt4, cbv[3], bsv[3], bbv[3], bufB);
  conv3x3<8, 8, 128, 256, 16, 1, 4, 0, 2><<<dim3(256, 4, 1), 256, 0, stream>>>(
      bufB, wt5, cbv[4], bsv[4], bbv[4], bufA);
  conv3x3<8, 8, 256, 256, 16, 1, 4, 2, 2><<<dim3(256, 4, 1), 256, 0, stream>>>(
      bufA, wt6, cbv[5], bsv[5], bbv[5], feats);

  // ---- experts ----
  gemm_head<256, 256, 1, 1><<<dim3(8, 16), 256, 0, stream>>>(
      feats, (size_t)0, exp_w1, exp_b1, exp_g1, exp_bb1, h1);
  gemm_head<128, 256, 1, 1><<<dim3(8, 16), 256, 0, stream>>>(
      h1, (size_t)512 * 256, exp_w2, exp_b2, exp_g2, exp_bb2, h2);
  gemm_head<128, 128, 0, 0><<<dim3(8, 16), 256, 0, stream>>>(
      h2, (size_t)512 * 128, exp_w3, exp_b3, nullptr, nullptr, emb);
  cls_softmax_k<<<2048, 256, 0, stream>>>(emb, cls_w, cls_b, lg, conf);

  // ---- gates ----
  gemm_head<64, 256, 1, 1><<<dim3(8, 16), 256, 0, stream>>>(
      feats, (size_t)0, gate_w1, gate_b1, gate_g1, gate_bb1, g1);
  gate23_k<<<2048, 256, 0, stream>>>(g1, gate_w2, gate_b2, gate_w3, gate_b3, sc);

  // ---- routing + outputs ----
  routing_k<<<1, 512, 0, stream>>>(sc, conf, lg, (float*)d_out);
}

// Round 3
// 2106.118 us; speedup vs baseline: 21.3641x; 21.3641x over previous
//
#include <hip/hip_runtime.h>

// ============================================================================
// ImprovedMoE fp32. R3 = R1 structure (proven 2260us) + 4 minimal changes:
//   1. compile-time channel loop (partial unroll -> s_load prefetch)
//   2. conv6 avgpool via shuffle (no 34.8KB sPool LDS)
//   3. odd LDS row stride WP=W+5 (kills 8-way bank conflicts)
//   4. B_PER=2 images/block for 8x8 convs (halves weight s_load per FMA)
// NO lambdas / register prefetch arrays (R2's scratch-spill disaster).
// ============================================================================

__global__ void wt_transpose_k(const float* __restrict__ w, float* __restrict__ wt,
                               int CI9, int CO) {
  int n = CI9 * CO;
  int idx = blockIdx.x * 256 + threadIdx.x;
  if (idx < n) {
    int co = idx % CO;
    int r  = idx / CO;            // r = ci*9 + tap
    wt[idx] = w[(size_t)co * CI9 + r];
  }
}

// ---------------------------------------------------------------------------
// Direct 3x3 SAME conv + bias + BN + ReLU, optional fused pool.
// POOL: 0 none, 1 2x2 maxpool, 2 global avg -> feats.
// LPR = W/PX lanes/row, WR = 64/LPR rows per wave tile.
// B_PER images per block (8x8 convs). Wave w owns co [co0, co0+CO_W).
// Weights stay in GLOBAL, read via wave-uniform pointer -> s_load (SMEM pipe,
// off the DS pipe). Inputs staged in LDS with odd row stride.
// ---------------------------------------------------------------------------
template<int H, int W, int CIN, int COUT, int CO_W, int PX, int CC, int POOL, int B_PER>
__global__ __launch_bounds__(256, 4) void conv3x3(
    const float* __restrict__ in, const float* __restrict__ wt,
    const float* __restrict__ cb, const float* __restrict__ bns,
    const float* __restrict__ bnb, float* __restrict__ out)
{
  constexpr int LPR = W / PX;
  constexpr int WR  = 64 / LPR;
  constexpr int WP  = W + 5;                 // ODD padded LDS row stride
  constexpr int BLOCK_CO = 4 * CO_W;
  constexpr int NC  = CIN / CC;
  static_assert(CIN % CC == 0, "CC must divide CIN");
  constexpr int CH_STRIDE  = (WR + 2) * WP;
  constexpr int IMG_STRIDE = CC * CH_STRIDE;

  __shared__ float sIn[B_PER * CC * (WR + 2) * WP];

  const int tid  = threadIdx.x;
  const int lane = tid & 63;
  const int wave = tid >> 6;
  const int bx   = blockIdx.x;
  const int co0  = blockIdx.y * BLOCK_CO + wave * CO_W;
  const int co_s = __builtin_amdgcn_readfirstlane(co0);
  const int r0   = blockIdx.z * WR;
  const int row  = lane / LPR;
  const int x0   = (lane % LPR) * PX;

  float acc[B_PER][PX][CO_W];
#pragma unroll
  for (int g = 0; g < B_PER; ++g)
#pragma unroll
    for (int p = 0; p < PX; ++p)
#pragma unroll
      for (int j = 0; j < CO_W; ++j) acc[g][p][j] = 0.f;

#pragma unroll 1
  for (int k = 0; k < NC; ++k) {
    const int c0 = k * CC;
    // ---- stage inputs: [B_PER][CC][WR+2][W+2] with zero halo ----
    constexpr int S = B_PER * CC * (WR + 2) * (W + 2);
    for (int idx = tid; idx < S; idx += 256) {
      int xx  = idx % (W + 2);
      int t   = idx / (W + 2);
      int rr  = t % (WR + 2);
      int t2  = t / (WR + 2);
      int c   = (B_PER == 1) ? t2 : (t2 % CC);
      int img = (B_PER == 1) ? 0  : (t2 / CC);
      int gr = r0 + rr - 1, gx = xx - 1;
      float v = 0.f;
      if (gr >= 0 && gr < H && gx >= 0 && gx < W)
        v = in[((size_t)(bx * B_PER + img) * CIN + c0 + c) * (H * W) + gr * W + gx];
      sIn[img * IMG_STRIDE + c * CH_STRIDE + rr * WP + xx] = v;
    }
    __syncthreads();
    // ---- compute ----
#pragma unroll 4
    for (int c = 0; c < CC; ++c) {
      float r[B_PER][3][PX + 2];
#pragma unroll
      for (int img = 0; img < B_PER; ++img) {
        const float* chp = &sIn[img * IMG_STRIDE + c * CH_STRIDE];
#pragma unroll
        for (int dy = 0; dy < 3; ++dy) {
          int base = (row + dy) * WP + x0;
#pragma unroll
          for (int i = 0; i < PX + 2; ++i) r[img][dy][i] = chp[base + i];
        }
      }
      const float* wp = wt + ((size_t)(c0 + c) * 9) * COUT + co_s;
#pragma unroll
      for (int t = 0; t < 9; ++t) {
        const int dy = t / 3, dx = t % 3;
        float w[CO_W];
#pragma unroll
        for (int j4 = 0; j4 < CO_W; j4 += 4) {
          float4 wv = *(const float4*)&wp[t * COUT + j4];
          w[j4] = wv.x; w[j4 + 1] = wv.y; w[j4 + 2] = wv.z; w[j4 + 3] = wv.w;
        }
#pragma unroll
        for (int img = 0; img < B_PER; ++img)
#pragma unroll
          for (int p = 0; p < PX; ++p) {
            float iv = r[img][dy][p + dx];
#pragma unroll
            for (int j = 0; j < CO_W; ++j)
              acc[img][p][j] = fmaf(iv, w[j], acc[img][p][j]);
          }
      }
    }
    __syncthreads();
  }

  // ---- epilogue: y = conv*s + (cb*s+bb); relu; pool ----
  float es[CO_W], eb[CO_W];
#pragma unroll
  for (int j = 0; j < CO_W; ++j) {
    float s_ = bns[co_s + j];
    es[j] = s_;
    eb[j] = fmaf(cb[co_s + j], s_, bnb[co_s + j]);
  }

  if constexpr (POOL == 0) {
    const int r = r0 + row;
#pragma unroll
    for (int img = 0; img < B_PER; ++img)
#pragma unroll
      for (int j = 0; j < CO_W; ++j) {
        float* op = out + (((size_t)(bx * B_PER + img) * COUT + co0 + j) * H + r) * W + x0;
        if constexpr (PX >= 4) {
#pragma unroll
          for (int p4 = 0; p4 < PX; p4 += 4) {
            float v0 = fmaxf(fmaf(acc[img][p4 + 0][j], es[j], eb[j]), 0.f);
            float v1 = fmaxf(fmaf(acc[img][p4 + 1][j], es[j], eb[j]), 0.f);
            float v2 = fmaxf(fmaf(acc[img][p4 + 2][j], es[j], eb[j]), 0.f);
            float v3 = fmaxf(fmaf(acc[img][p4 + 3][j], es[j], eb[j]), 0.f);
            *(float4*)(op + p4) = make_float4(v0, v1, v2, v3);
          }
        } else {
          op[0] = fmaxf(fmaf(acc[img][0][j], es[j], eb[j]), 0.f);
        }
      }
  } else if constexpr (POOL == 1) {   // PX==8 or PX==4, B_PER==1
    const int r = r0 + row;
#pragma unroll
    for (int j = 0; j < CO_W; ++j) {
      float pm[PX / 2];
#pragma unroll
      for (int p2 = 0; p2 < PX / 2; ++p2) {
        float v0 = fmaxf(fmaf(acc[0][2 * p2][j], es[j], eb[j]), 0.f);
        float v1 = fmaxf(fmaf(acc[0][2 * p2 + 1][j], es[j], eb[j]), 0.f);
        float m  = fmaxf(v0, v1);
        float om = __shfl_xor(m, LPR, 64);   // partner row (r ^ 1)
        pm[p2]   = fmaxf(m, om);
      }
      if ((row & 1) == 0) {
        float* op = out + (((size_t)bx * COUT + co0 + j) * (H / 2) + (r >> 1)) * (W / 2) + (x0 >> 1);
        if constexpr (PX / 2 == 4)
          *(float4*)op = make_float4(pm[0], pm[1], pm[2], pm[3]);
        else if constexpr (PX / 2 == 2)
          *(float2*)op = make_float2(pm[0], pm[1]);
        else
          op[0] = pm[0];
      }
    }
  } else {  // POOL == 2: global avg over 64 px (PX==1, lane==pixel), shuffle
    float myv = 0.f;
#pragma unroll
    for (int img = 0; img < B_PER; ++img)
#pragma unroll
      for (int j = 0; j < CO_W; ++j) {
        float v = fmaxf(fmaf(acc[img][0][j], es[j], eb[j]), 0.f);
#pragma unroll
        for (int s = 32; s >= 1; s >>= 1) v += __shfl_xor(v, s, 64);
        if (lane == img * CO_W + j) myv = v * (1.f / 64.f);
      }
    if (lane < B_PER * CO_W) {
      int img = lane / CO_W, j = lane % CO_W;
      out[(size_t)(bx * B_PER + img) * COUT + co0 + j] = myv;
    }
  }
}

// ---------------------------------------------------------------------------
// Batched head GEMM (unchanged from R1, verified correct).
// ---------------------------------------------------------------------------
template<int O, int K, int LN, int RELU>
__global__ __launch_bounds__(256, 4) void gemm_head(
    const float* __restrict__ A, size_t aStrideE,
    const float* __restrict__ Wm, const float* __restrict__ bias,
    const float* __restrict__ g, const float* __restrict__ bb,
    float* __restrict__ out)
{
  constexpr int KC  = (O >= 256) ? 32 : 64;
  constexpr int WST = O + 4;
  constexpr int TO  = O / 16;
  __shared__ float sA[KC * 68];
  __shared__ float sW[KC * WST];
  __shared__ float mArr[64], rArr[64];

  const int tid  = threadIdx.x;
  const int lane = tid & 63;
  const int wave = tid >> 6;
  const int e    = blockIdx.y;
  const int b0g  = blockIdx.x * 64;
  const int bl   = (lane & 15) * 4;
  const int ol   = wave * (O / 4) + (lane >> 4) * TO;

  const float* Ae = A + (size_t)e * aStrideE;
  const float* We = Wm + (size_t)e * O * K;

  float acc[4][TO];
#pragma unroll
  for (int i = 0; i < 4; ++i)
#pragma unroll
    for (int j = 0; j < TO; ++j) acc[i][j] = 0.f;

  for (int k0 = 0; k0 < K; k0 += KC) {
    for (int idx = tid; idx < 64 * KC; idx += 256) {
      int kk = idx % KC, bb_ = idx / KC;
      sA[kk * 68 + bb_] = Ae[(size_t)(b0g + bb_) * K + k0 + kk];
    }
    for (int idx = tid; idx < O * KC; idx += 256) {
      int kk = idx % KC, oo = idx / KC;
      sW[kk * WST + oo] = We[(size_t)oo * K + k0 + kk];
    }
    __syncthreads();
#pragma unroll 4
    for (int kk = 0; kk < KC; ++kk) {
      float4 av = *(const float4*)&sA[kk * 68 + bl];
      float a4[4] = {av.x, av.y, av.z, av.w};
#pragma unroll
      for (int j4 = 0; j4 < TO; j4 += 4) {
        float4 wv = *(const float4*)&sW[kk * WST + ol + j4];
        float w4[4] = {wv.x, wv.y, wv.z, wv.w};
#pragma unroll
        for (int i = 0; i < 4; ++i)
#pragma unroll
          for (int jj = 0; jj < 4; ++jj)
            acc[i][j4 + jj] = fmaf(a4[i], w4[jj], acc[i][j4 + jj]);
      }
    }
    __syncthreads();
  }

  const float* bi = bias + (size_t)e * O;
#pragma unroll
  for (int i = 0; i < 4; ++i)
#pragma unroll
    for (int j = 0; j < TO; ++j) acc[i][j] += bi[ol + j];

  if constexpr (LN) {
    float* redS = sA;
    float* redQ = sA + 1024;
    const int grp = wave * 4 + (lane >> 4);
#pragma unroll
    for (int i = 0; i < 4; ++i) {
      float s = 0.f, q = 0.f;
#pragma unroll
      for (int j = 0; j < TO; ++j) { s += acc[i][j]; q += acc[i][j] * acc[i][j]; }
      redS[(bl + i) * 16 + grp] = s;
      redQ[(bl + i) * 16 + grp] = q;
    }
    __syncthreads();
    if (tid < 64) {
      float s = 0.f, q = 0.f;
#pragma unroll
      for (int gi = 0; gi < 16; ++gi) { s += redS[tid * 16 + gi]; q += redQ[tid * 16 + gi]; }
      float mean = s * (1.f / O);
      float var  = q * (1.f / O) - mean * mean;
      mArr[tid] = mean;
      rArr[tid] = rsqrtf(var + 1e-5f);
    }
    __syncthreads();
    const float* gp  = g + (size_t)e * O;
    const float* bbp = bb + (size_t)e * O;
#pragma unroll
    for (int i = 0; i < 4; ++i) {
      float mean = mArr[bl + i], rstd = rArr[bl + i];
#pragma unroll
      for (int j = 0; j < TO; ++j)
        acc[i][j] = (acc[i][j] - mean) * rstd * gp[ol + j] + bbp[ol + j];
    }
  }
  if constexpr (RELU) {
#pragma unroll
    for (int i = 0; i < 4; ++i)
#pragma unroll
      for (int j = 0; j < TO; ++j) acc[i][j] = fmaxf(acc[i][j], 0.f);
  }
#pragma unroll
  for (int i = 0; i < 4; ++i) {
    float* op = out + ((size_t)e * 512 + b0g + bl + i) * O + ol;
#pragma unroll
    for (int j4 = 0; j4 < TO; j4 += 4)
      *(float4*)(op + j4) = make_float4(acc[i][j4], acc[i][j4 + 1], acc[i][j4 + 2], acc[i][j4 + 3]);
  }
}

__global__ void cls_softmax_k(const float* __restrict__ embeds,
                              const float* __restrict__ cw,
                              const float* __restrict__ cbias,
                              float* __restrict__ logits_e,
                              float* __restrict__ conf)
{
  int wv   = (blockIdx.x * 256 + threadIdx.x) >> 6;
  int lane = threadIdx.x & 63;
  int b = wv >> 4, e = wv & 15;
  const float* ep = embeds + ((size_t)e * 512 + b) * 128;
  float e0 = ep[lane], e1 = ep[lane + 64];
  float l[10];
#pragma unroll
  for (int o = 0; o < 10; ++o) {
    const float* wp = cw + ((size_t)e * 10 + o) * 128;
    l[o] = e0 * wp[lane] + e1 * wp[lane + 64];
  }
#pragma unroll
  for (int s = 32; s >= 1; s >>= 1)
#pragma unroll
    for (int o = 0; o < 10; ++o) l[o] += __shfl_xor(l[o], s, 64);
#pragma unroll
  for (int o = 0; o < 10; ++o) l[o] += cbias[e * 10 + o];
  float m = l[0];
#pragma unroll
  for (int o = 1; o < 10; ++o) m = fmaxf(m, l[o]);
  float p[10], sum = 0.f;
#pragma unroll
  for (int o = 0; o < 10; ++o) { p[o] = expf(l[o] - m); sum += p[o]; }
  float inv = 1.f / sum, ent = 0.f;
#pragma unroll
  for (int o = 0; o < 10; ++o) { float pp = p[o] * inv; ent -= pp * logf(pp + 1e-12f); }
  if (lane == 0) {
    conf[b * 16 + e] = -ent;
#pragma unroll
    for (int o = 0; o < 10; ++o) logits_e[((size_t)b * 16 + e) * 10 + o] = l[o];
  }
}

__global__ void gate23_k(const float* __restrict__ g1, const float* __restrict__ w2,
                         const float* __restrict__ b2, const float* __restrict__ w3,
                         const float* __restrict__ b3, float* __restrict__ scores)
{
  int wv   = (blockIdx.x * 256 + threadIdx.x) >> 6;
  int lane = threadIdx.x & 63;
  int b = wv >> 4, e = wv & 15;
  float gv = g1[((size_t)e * 512 + b) * 64 + lane];
  const float* w3p = w3 + e * 32;
  float sc = 0.f;
#pragma unroll
  for (int o = 0; o < 32; ++o) {
    float t = gv * w2[((size_t)e * 32 + o) * 64 + lane];
#pragma unroll
    for (int s = 32; s >= 1; s >>= 1) t += __shfl_xor(t, s, 64);
    float g2v = fmaxf(t + b2[e * 32 + o], 0.f);
    sc = fmaf(g2v, w3p[o], sc);
  }
  if (lane == 0) scores[b * 16 + e] = sc + b3[e];   // RTEMP == 1
}

__global__ void routing_k(const float* __restrict__ scores, const float* __restrict__ conf,
                          const float* __restrict__ logits_e, float* __restrict__ out)
{
  __shared__ int t2[512];
  __shared__ int chs[512];
  const int tid = threadIdx.x;

  if (tid < 512) {
    int b = tid;
    float v0 = -3.4e38f, v1 = -3.4e38f;
    int i0 = 0, i1 = 0;
#pragma unroll
    for (int e = 0; e < 16; ++e) {
      float s = scores[b * 16 + e];
      float c = conf[b * 16 + e];
      float v = 0.7f * s + 0.3f * c - 0.125f;
      out[5120 + b * 16 + e] = v;   // balanced output
      if (v > v0) { v1 = v0; i1 = i0; v0 = v; i0 = e; }
      else if (v > v1) { v1 = v; i1 = e; }
    }
    t2[b] = i0 | (i1 << 8);
  }
  __syncthreads();

  if (tid < 64) {
    int lane = tid;
    int cnt = 0;
    int pk[8];
#pragma unroll
    for (int k = 0; k < 8; ++k) pk[k] = t2[k * 64 + lane];
#pragma unroll 1
    for (int k = 0; k < 8; ++k) {
      for (int j = 0; j < 64; ++j) {
        int pair = __shfl(pk[k], j, 64);
        int i0 = pair & 0xff, i1 = (pair >> 8) & 0xff;
        int c0 = __shfl(cnt, i0, 64);
        int c1 = __shfl(cnt, i1, 64);
        int ch = (c0 < 64) ? i0 : ((c1 < 64) ? i1 : ((c0 <= c1) ? i0 : i1));
        cnt += (lane == ch) ? 1 : 0;
        if (lane == 0) chs[k * 64 + j] = ch;
      }
    }
  }
  __syncthreads();

  if (tid < 512) {
    int b = tid;
    int ch = chs[b];
#pragma unroll
    for (int e = 0; e < 16; ++e)
      out[13312 + b * 16 + e] = (e == ch) ? 1.0f : 0.0f;   // D
#pragma unroll
    for (int o = 0; o < 10; ++o)
      out[b * 10 + o] = logits_e[((size_t)b * 16 + ch) * 10 + o];  // final_logits
  }
}

// ============================================================================
extern "C" void kernel_launch(void* const* d_in, const int* in_sizes, int n_in,
                              void* d_out, int out_size, void* d_ws, size_t ws_size,
                              hipStream_t stream) {
  (void)in_sizes; (void)n_in; (void)out_size; (void)ws_size;

  const float* x = (const float*)d_in[0];
  const float *cw[6], *cbv[6], *bsv[6], *bbv[6];
  for (int i = 0; i < 6; ++i) {
    cw[i]  = (const float*)d_in[1 + 4 * i];
    cbv[i] = (const float*)d_in[2 + 4 * i];
    bsv[i] = (const float*)d_in[3 + 4 * i];
    bbv[i] = (const float*)d_in[4 + 4 * i];
  }
  const float* gate_w1  = (const float*)d_in[25];
  const float* gate_b1  = (const float*)d_in[26];
  const float* gate_g1  = (const float*)d_in[27];
  const float* gate_bb1 = (const float*)d_in[28];
  const float* gate_w2  = (const float*)d_in[29];
  const float* gate_b2  = (const float*)d_in[30];
  const float* gate_w3  = (const float*)d_in[31];
  const float* gate_b3  = (const float*)d_in[32];
  const float* exp_w1   = (const float*)d_in[33];
  const float* exp_b1   = (const float*)d_in[34];
  const float* exp_g1   = (const float*)d_in[35];
  const float* exp_bb1  = (const float*)d_in[36];
  const float* exp_w2   = (const float*)d_in[37];
  const float* exp_b2   = (const float*)d_in[38];
  const float* exp_g2   = (const float*)d_in[39];
  const float* exp_bb2  = (const float*)d_in[40];
  const float* exp_w3   = (const float*)d_in[41];
  const float* exp_b3   = (const float*)d_in[42];
  const float* cls_w    = (const float*)d_in[43];
  const float* cls_b    = (const float*)d_in[44];

  float* ws = (float*)d_ws;
  size_t o_wt1 = 0;
  size_t o_wt2 = o_wt1 + 1728;
  size_t o_wt3 = o_wt2 + 36864;
  size_t o_wt4 = o_wt3 + 73728;
  size_t o_wt5 = o_wt4 + 147456;
  size_t o_wt6 = o_wt5 + 294912;
  size_t o_bufA  = o_wt6 + 589824;
  size_t o_bufB  = o_bufA + 33554432ull;
  size_t o_feats = o_bufB + 8388608ull;
  size_t o_h1    = o_feats + 131072;
  size_t o_h2    = o_h1 + 2097152;
  size_t o_emb   = o_h2 + 1048576;
  size_t o_g1    = o_emb + 1048576;
  size_t o_lg    = o_g1 + 524288;
  size_t o_conf  = o_lg + 81920;
  size_t o_sc    = o_conf + 8192;

  float* wt1 = ws + o_wt1; float* wt2 = ws + o_wt2; float* wt3 = ws + o_wt3;
  float* wt4 = ws + o_wt4; float* wt5 = ws + o_wt5; float* wt6 = ws + o_wt6;
  float* bufA = ws + o_bufA; float* bufB = ws + o_bufB;
  float* feats = ws + o_feats; float* h1 = ws + o_h1; float* h2 = ws + o_h2;
  float* emb = ws + o_emb; float* g1 = ws + o_g1; float* lg = ws + o_lg;
  float* conf = ws + o_conf; float* sc = ws + o_sc;

  auto cdiv = [](int a, int b) { return (a + b - 1) / b; };

  // ---- weight transposes ----
  wt_transpose_k<<<cdiv(27 * 64, 256), 256, 0, stream>>>(cw[0], wt1, 27, 64);
  wt_transpose_k<<<cdiv(576 * 64, 256), 256, 0, stream>>>(cw[1], wt2, 576, 64);
  wt_transpose_k<<<cdiv(576 * 128, 256), 256, 0, stream>>>(cw[2], wt3, 576, 128);
  wt_transpose_k<<<cdiv(1152 * 128, 256), 256, 0, stream>>>(cw[3], wt4, 1152, 128);
  wt_transpose_k<<<cdiv(1152 * 256, 256), 256, 0, stream>>>(cw[4], wt5, 1152, 256);
  wt_transpose_k<<<cdiv(2304 * 256, 256), 256, 0, stream>>>(cw[5], wt6, 2304, 256);

  // ---- trunk ----  <H, W, CIN, COUT, CO_W, PX, CC, POOL, B_PER>
  conv3x3<32, 32, 3, 64, 8, 8, 3, 0, 1><<<dim3(512, 2, 2), 256, 0, stream>>>(
      x, wt1, cbv[0], bsv[0], bbv[0], bufA);
  conv3x3<32, 32, 64, 64, 8, 8, 8, 1, 1><<<dim3(512, 2, 2), 256, 0, stream>>>(
      bufA, wt2, cbv[1], bsv[1], bbv[1], bufB);
  conv3x3<16, 16, 64, 128, 16, 4, 8, 0, 1><<<dim3(512, 2, 1), 256, 0, stream>>>(
      bufB, wt3, cbv[2], bsv[2], bbv[2], bufA);
  conv3x3<16, 16, 128, 128, 16, 4, 8, 1, 1><<<dim3(512, 2, 1), 256, 0, stream>>>(
      bufA, wt4, cbv[3], bsv[3], bbv[3], bufB);
  conv3x3<8, 8, 128, 256, 16, 1, 8, 0, 2><<<dim3(256, 4, 1), 256, 0, stream>>>(
      bufB, wt5, cbv[4], bsv[4], bbv[4], bufA);
  conv3x3<8, 8, 256, 256, 16, 1, 8, 2, 2><<<dim3(256, 4, 1), 256, 0, stream>>>(
      bufA, wt6, cbv[5], bsv[5], bbv[5], feats);

  // ---- experts ----
  gemm_head<256, 256, 1, 1><<<dim3(8, 16), 256, 0, stream>>>(
      feats, (size_t)0, exp_w1, exp_b1, exp_g1, exp_bb1, h1);
  gemm_head<128, 256, 1, 1><<<dim3(8, 16), 256, 0, stream>>>(
      h1, (size_t)512 * 256, exp_w2, exp_b2, exp_g2, exp_bb2, h2);
  gemm_head<128, 128, 0, 0><<<dim3(8, 16), 256, 0, stream>>>(
      h2, (size_t)512 * 128, exp_w3, exp_b3, nullptr, nullptr, emb);
  cls_softmax_k<<<2048, 256, 0, stream>>>(emb, cls_w, cls_b, lg, conf);

  // ---- gates ----
  gemm_head<64, 256, 1, 1><<<dim3(8, 16), 256, 0, stream>>>(
      feats, (size_t)0, gate_w1, gate_b1, gate_g1, gate_bb1, g1);
  gate23_k<<<2048, 256, 0, stream>>>(g1, gate_w2, gate_b2, gate_w3, gate_b3, sc);

  // ---- routing + outputs ----
  routing_k<<<1, 512, 0, stream>>>(sc, conf, lg, (float*)d_out);
}

// Round 4
// 1919.096 us; speedup vs baseline: 23.4461x; 1.0975x over previous
//
#include <hip/hip_runtime.h>

// ============================================================================
// ImprovedMoE R4: conv2..conv6 on matrix cores via fp16x2 split emulation
// (x = hi + lo fp16; D += Ah*Bh + Al*Bh + Ah*Bl; fp32-grade precision at
// ~793 TF effective ceiling). Activations = hi/lo fp16 planes, NHWC,
// unpadded; halo via clamped+masked loads; A/B frags direct from global
// (no LDS, no barriers). BN/ReLU/pool fused in C-layout epilogues.
// conv1 fp32-vector -> split planes. Heads/routing = R1 (verified).
// Workspace: exactly 192,142,080 B (== R3 proven footprint).
// ============================================================================

typedef _Float16 h16;
typedef _Float16 half8 __attribute__((ext_vector_type(8)));
typedef float f32x16 __attribute__((ext_vector_type(16)));

__device__ __forceinline__ void split2f(float x, h16& hh, h16& ll) {
  h16 a = (h16)x;
  hh = a;
  ll = (h16)(x - (float)a);
}

// ---- conv1 weight transpose: w[co][ci*9+tap] -> wt[ci*9+tap][co] ----
__global__ void wt_transpose_k(const float* __restrict__ w, float* __restrict__ wt,
                               int CI9, int CO) {
  int n = CI9 * CO;
  int idx = blockIdx.x * 256 + threadIdx.x;
  if (idx < n) {
    int co = idx % CO;
    int r  = idx / CO;
    wt[idx] = w[(size_t)co * CI9 + r];
  }
}

// ---- split conv weights: w[co][ci][tap] -> wh/wl[tap][co][ci] (fp16 hi/lo) ----
__global__ void wsplit_k(const float* __restrict__ w, h16* __restrict__ wh,
                         h16* __restrict__ wl, int CIN, int COUT) {
  int total = 9 * COUT * CIN;
  int idx = blockIdx.x * 256 + threadIdx.x;
  if (idx >= total) return;
  int ci = idx % CIN;
  int t  = idx / CIN;
  int co = t % COUT;
  int tap = t / COUT;
  float v = w[((size_t)co * CIN + ci) * 9 + tap];
  h16 hh, ll;
  split2f(v, hh, ll);
  wh[idx] = hh;   // idx == (tap*COUT + co)*CIN + ci
  wl[idx] = ll;
}

// ---- conv1: 3->64, 32x32, fp32 vector; outputs hi/lo fp16 NHWC planes ----
__global__ __launch_bounds__(256) void conv1_k(
    const float* __restrict__ x, const float* __restrict__ wt,
    const float* __restrict__ cb, const float* __restrict__ bns,
    const float* __restrict__ bnb, h16* __restrict__ oh, h16* __restrict__ ol)
{
  __shared__ float sx[3 * 34 * 34];
  const int tid = threadIdx.x;
  const int img = blockIdx.x;
  for (int idx = tid; idx < 3 * 34 * 34; idx += 256) {
    int xx = idx % 34;
    int t  = idx / 34;
    int rr = t % 34;
    int c  = t / 34;
    int gr = rr - 1, gx = xx - 1;
    float v = 0.f;
    if (gr >= 0 && gr < 32 && gx >= 0 && gx < 32)
      v = x[((size_t)(img * 3 + c) * 32 + gr) * 32 + gx];
    sx[(c * 34 + rr) * 34 + xx] = v;
  }
  __syncthreads();
#pragma unroll 1
  for (int k = 0; k < 4; ++k) {
    int px = k * 256 + tid;
    int yy = px >> 5, xx = px & 31;
    float in27[27];
#pragma unroll
    for (int c = 0; c < 3; ++c)
#pragma unroll
      for (int dy = 0; dy < 3; ++dy)
#pragma unroll
        for (int dx = 0; dx < 3; ++dx)
          in27[c * 9 + dy * 3 + dx] = sx[(c * 34 + yy + dy) * 34 + xx + dx];
#pragma unroll 1
    for (int co8 = 0; co8 < 8; ++co8) {
      h16 hb[8], lb[8];
#pragma unroll
      for (int j = 0; j < 8; ++j) {
        int co = co8 * 8 + j;
        float acc = 0.f;
#pragma unroll
        for (int t = 0; t < 27; ++t) acc = fmaf(in27[t], wt[t * 64 + co], acc);
        float s = bns[co];
        float yv = fmaxf(fmaf(acc + cb[co], s, bnb[co]), 0.f);
        split2f(yv, hb[j], lb[j]);
      }
      size_t o = ((size_t)img * 1024 + px) * 64 + co8 * 8;
      *(half8*)&oh[o] = *(half8*)hb;
      *(half8*)&ol[o] = *(half8*)lb;
    }
  }
}

// ---------------------------------------------------------------------------
// MFMA conv: 3x3 SAME, fp16x2-split, tap-decomposed implicit GEMM.
// Wave tile: (MT*32) px x 64 co (2 n-tiles). Block: MW m-waves x NW n-waves.
// POOL: 0 none, 1 maxpool2x2 (RPT==1: cross-tile y-pair; RPT==2: intra-reg),
//       2 global avg -> feats.
// A/B frags loaded straight from global (L1/L2); no LDS, no barriers.
// ---------------------------------------------------------------------------
template<int H, int W, int CIN, int COUT, int MT, int MW, int NW, int POOL>
__global__ __launch_bounds__(256, 2) void conv_mfma(
    const h16* __restrict__ Ah, const h16* __restrict__ Al,
    const h16* __restrict__ Wh, const h16* __restrict__ Wl,
    const float* __restrict__ cb, const float* __restrict__ bns,
    const float* __restrict__ bnb,
    h16* __restrict__ Oh, h16* __restrict__ Ol, float* __restrict__ feats)
{
  constexpr int TPI  = (H * W) / 32;      // m-tiles per image
  constexpr int RPT  = 32 / W;            // rows per m-tile
  constexpr int IPB  = (MT * MW * 32 >= H * W) ? (MT * MW * 32) / (H * W) : 1;
  constexpr int KC   = CIN / 16;
  constexpr int LOGW = (W == 32) ? 5 : (W == 16) ? 4 : 3;

  const int tid  = threadIdx.x;
  const int lane = tid & 63;
  const int wave = tid >> 6;
  const int half = lane >> 5;
  const int col  = lane & 31;
  const int wm   = wave % MW;
  const int wn   = wave / MW;
  const int co0  = blockIdx.z * (NW * 64) + wn * 64;

  int aoff[MT], ty[MT], tx[MT], img_t[MT], rw0[MT];
#pragma unroll
  for (int t = 0; t < MT; ++t) {
    int gt   = blockIdx.y * (MT * MW) + wm * MT + t;
    int img  = blockIdx.x * IPB + gt / TPI;
    int row0 = (gt % TPI) * RPT;
    int y = row0 + (col >> LOGW);
    int x = col & (W - 1);
    img_t[t] = img; rw0[t] = row0; ty[t] = y; tx[t] = x;
    aoff[t] = ((img * H + y) * W + x) * CIN + half * 8;
  }
  int boff[2];
#pragma unroll
  for (int n = 0; n < 2; ++n)
    boff[n] = (co0 + n * 32 + col) * CIN + half * 8;

  half8 hz;
#pragma unroll
  for (int i = 0; i < 8; ++i) hz[i] = (h16)0.f;

  f32x16 acc[MT][2];
#pragma unroll
  for (int t = 0; t < MT; ++t)
#pragma unroll
    for (int n = 0; n < 2; ++n)
#pragma unroll
      for (int i = 0; i < 16; ++i) acc[t][n][i] = 0.f;

#pragma unroll 1
  for (int ck = 0; ck < KC; ++ck) {
    const int cko = ck * 16;
#pragma unroll
    for (int tap = 0; tap < 9; ++tap) {
      const int dy = tap / 3 - 1, dx = tap % 3 - 1;
      const int ashift = (dy * W + dx) * CIN + cko;
      half8 bh[2], bl[2];
#pragma unroll
      for (int n = 0; n < 2; ++n) {
        int bi = tap * (COUT * CIN) + boff[n] + cko;
        bh[n] = *(const half8*)(Wh + bi);
        bl[n] = *(const half8*)(Wl + bi);
      }
      half8 ah[MT], al[MT];
#pragma unroll
      for (int t = 0; t < MT; ++t) {
        bool v = ((unsigned)(ty[t] + dy) < (unsigned)H) &&
                 ((unsigned)(tx[t] + dx) < (unsigned)W);
        int ai = v ? (aoff[t] + ashift) : 0;
        half8 h = *(const half8*)(Ah + ai);
        half8 l = *(const half8*)(Al + ai);
        ah[t] = v ? h : hz;
        al[t] = v ? l : hz;
      }
#pragma unroll
      for (int t = 0; t < MT; ++t)
#pragma unroll
        for (int n = 0; n < 2; ++n) {
          acc[t][n] = __builtin_amdgcn_mfma_f32_32x32x16_f16(ah[t], bh[n], acc[t][n], 0, 0, 0);
          acc[t][n] = __builtin_amdgcn_mfma_f32_32x32x16_f16(al[t], bh[n], acc[t][n], 0, 0, 0);
          acc[t][n] = __builtin_amdgcn_mfma_f32_32x32x16_f16(ah[t], bl[n], acc[t][n], 0, 0, 0);
        }
    }
  }

  // ---- epilogue: y = acc*s + (cb*s+bb), relu, pool, split-store ----
  // C/D layout: col(co)=lane&31, row(px-in-tile)=(reg&3)+4*half+8*(reg>>2)
#pragma unroll
  for (int n = 0; n < 2; ++n) {
    const int co = co0 + n * 32 + col;
    const float es = bns[co];
    const float eb = fmaf(cb[co], es, bnb[co]);

    if constexpr (POOL == 0) {
#pragma unroll
      for (int t = 0; t < MT; ++t) {
#pragma unroll
        for (int r = 0; r < 16; ++r) {
          float v = fmaxf(fmaf(acc[t][n][r], es, eb), 0.f);
          int m = (r & 3) + 4 * half + 8 * (r >> 2);
          int y = rw0[t] + (m >> LOGW);
          int x = m & (W - 1);
          size_t oi = (((size_t)img_t[t] * H + y) * W + x) * COUT + co;
          h16 hh, ll; split2f(v, hh, ll);
          Oh[oi] = hh; Ol[oi] = ll;
        }
      }
    } else if constexpr (POOL == 1 && RPT == 1) {   // conv2: y-pair across tiles
#pragma unroll
      for (int tp = 0; tp < MT / 2; ++tp) {
        const int t0 = 2 * tp, t1 = 2 * tp + 1;
        const int yq = rw0[t0] >> 1;
#pragma unroll
        for (int r = 0; r < 16; r += 2) {
          float v00 = fmaxf(fmaf(acc[t0][n][r],     es, eb), 0.f);
          float v01 = fmaxf(fmaf(acc[t0][n][r + 1], es, eb), 0.f);
          float v10 = fmaxf(fmaf(acc[t1][n][r],     es, eb), 0.f);
          float v11 = fmaxf(fmaf(acc[t1][n][r + 1], es, eb), 0.f);
          float mv = fmaxf(fmaxf(v00, v01), fmaxf(v10, v11));
          int xq = ((r & 3) >> 1) + 2 * half + 4 * (r >> 2);
          size_t oi = (((size_t)img_t[t0] * (H / 2) + yq) * (W / 2) + xq) * COUT + co;
          h16 hh, ll; split2f(mv, hh, ll);
          Oh[oi] = hh; Ol[oi] = ll;
        }
      }
    } else if constexpr (POOL == 1) {               // conv4 (RPT==2): intra-reg
#pragma unroll
      for (int t = 0; t < MT; ++t) {
        const int yq = rw0[t] >> 1;
#pragma unroll
        for (int r = 0; r < 8; r += 2) {            // r in {0,2,4,6}
          float v00 = fmaxf(fmaf(acc[t][n][r],     es, eb), 0.f);
          float v01 = fmaxf(fmaf(acc[t][n][r + 1], es, eb), 0.f);
          float v10 = fmaxf(fmaf(acc[t][n][r + 8], es, eb), 0.f);
          float v11 = fmaxf(fmaf(acc[t][n][r + 9], es, eb), 0.f);
          float mv = fmaxf(fmaxf(v00, v01), fmaxf(v10, v11));
          int xq = ((r & 3) >> 1) + 2 * half + 4 * (r >> 2);
          size_t oi = (((size_t)img_t[t] * (H / 2) + yq) * (W / 2) + xq) * COUT + co;
          h16 hh, ll; split2f(mv, hh, ll);
          Oh[oi] = hh; Ol[oi] = ll;
        }
      }
    } else {                                        // POOL==2: avg -> feats (MT==2 == 1 img)
      float s = 0.f;
#pragma unroll
      for (int t = 0; t < MT; ++t)
#pragma unroll
        for (int r = 0; r < 16; ++r)
          s += fmaxf(fmaf(acc[t][n][r], es, eb), 0.f);
      s += __shfl_xor(s, 32, 64);
      if (half == 0) feats[(size_t)img_t[0] * 256 + co] = s * (1.f / 64.f);
    }
  }
}

// ---------------------------------------------------------------------------
// Batched head GEMM (R1, verified).
// ---------------------------------------------------------------------------
template<int O, int K, int LN, int RELU>
__global__ __launch_bounds__(256, 4) void gemm_head(
    const float* __restrict__ A, size_t aStrideE,
    const float* __restrict__ Wm, const float* __restrict__ bias,
    const float* __restrict__ g, const float* __restrict__ bb,
    float* __restrict__ out)
{
  constexpr int KC  = (O >= 256) ? 32 : 64;
  constexpr int WST = O + 4;
  constexpr int TO  = O / 16;
  __shared__ float sA[KC * 68];
  __shared__ float sW[KC * WST];
  __shared__ float mArr[64], rArr[64];

  const int tid  = threadIdx.x;
  const int lane = tid & 63;
  const int wave = tid >> 6;
  const int e    = blockIdx.y;
  const int b0g  = blockIdx.x * 64;
  const int bl   = (lane & 15) * 4;
  const int ol   = wave * (O / 4) + (lane >> 4) * TO;

  const float* Ae = A + (size_t)e * aStrideE;
  const float* We = Wm + (size_t)e * O * K;

  float acc[4][TO];
#pragma unroll
  for (int i = 0; i < 4; ++i)
#pragma unroll
    for (int j = 0; j < TO; ++j) acc[i][j] = 0.f;

  for (int k0 = 0; k0 < K; k0 += KC) {
    for (int idx = tid; idx < 64 * KC; idx += 256) {
      int kk = idx % KC, bb_ = idx / KC;
      sA[kk * 68 + bb_] = Ae[(size_t)(b0g + bb_) * K + k0 + kk];
    }
    for (int idx = tid; idx < O * KC; idx += 256) {
      int kk = idx % KC, oo = idx / KC;
      sW[kk * WST + oo] = We[(size_t)oo * K + k0 + kk];
    }
    __syncthreads();
#pragma unroll 4
    for (int kk = 0; kk < KC; ++kk) {
      float4 av = *(const float4*)&sA[kk * 68 + bl];
      float a4[4] = {av.x, av.y, av.z, av.w};
#pragma unroll
      for (int j4 = 0; j4 < TO; j4 += 4) {
        float4 wv = *(const float4*)&sW[kk * WST + ol + j4];
        float w4[4] = {wv.x, wv.y, wv.z, wv.w};
#pragma unroll
        for (int i = 0; i < 4; ++i)
#pragma unroll
          for (int jj = 0; jj < 4; ++jj)
            acc[i][j4 + jj] = fmaf(a4[i], w4[jj], acc[i][j4 + jj]);
      }
    }
    __syncthreads();
  }

  const float* bi = bias + (size_t)e * O;
#pragma unroll
  for (int i = 0; i < 4; ++i)
#pragma unroll
    for (int j = 0; j < TO; ++j) acc[i][j] += bi[ol + j];

  if constexpr (LN) {
    float* redS = sA;
    float* redQ = sA + 1024;
    const int grp = wave * 4 + (lane >> 4);
#pragma unroll
    for (int i = 0; i < 4; ++i) {
      float s = 0.f, q = 0.f;
#pragma unroll
      for (int j = 0; j < TO; ++j) { s += acc[i][j]; q += acc[i][j] * acc[i][j]; }
      redS[(bl + i) * 16 + grp] = s;
      redQ[(bl + i) * 16 + grp] = q;
    }
    __syncthreads();
    if (tid < 64) {
      float s = 0.f, q = 0.f;
#pragma unroll
      for (int gi = 0; gi < 16; ++gi) { s += redS[tid * 16 + gi]; q += redQ[tid * 16 + gi]; }
      float mean = s * (1.f / O);
      float var  = q * (1.f / O) - mean * mean;
      mArr[tid] = mean;
      rArr[tid] = rsqrtf(var + 1e-5f);
    }
    __syncthreads();
    const float* gp  = g + (size_t)e * O;
    const float* bbp = bb + (size_t)e * O;
#pragma unroll
    for (int i = 0; i < 4; ++i) {
      float mean = mArr[bl + i], rstd = rArr[bl + i];
#pragma unroll
      for (int j = 0; j < TO; ++j)
        acc[i][j] = (acc[i][j] - mean) * rstd * gp[ol + j] + bbp[ol + j];
    }
  }
  if constexpr (RELU) {
#pragma unroll
    for (int i = 0; i < 4; ++i)
#pragma unroll
      for (int j = 0; j < TO; ++j) acc[i][j] = fmaxf(acc[i][j], 0.f);
  }
#pragma unroll
  for (int i = 0; i < 4; ++i) {
    float* op = out + ((size_t)e * 512 + b0g + bl + i) * O + ol;
#pragma unroll
    for (int j4 = 0; j4 < TO; j4 += 4)
      *(float4*)(op + j4) = make_float4(acc[i][j4], acc[i][j4 + 1], acc[i][j4 + 2], acc[i][j4 + 3]);
  }
}

__global__ void cls_softmax_k(const float* __restrict__ embeds,
                              const float* __restrict__ cw,
                              const float* __restrict__ cbias,
                              float* __restrict__ logits_e,
                              float* __restrict__ conf)
{
  int wv   = (blockIdx.x * 256 + threadIdx.x) >> 6;
  int lane = threadIdx.x & 63;
  int b = wv >> 4, e = wv & 15;
  const float* ep = embeds + ((size_t)e * 512 + b) * 128;
  float e0 = ep[lane], e1 = ep[lane + 64];
  float l[10];
#pragma unroll
  for (int o = 0; o < 10; ++o) {
    const float* wp = cw + ((size_t)e * 10 + o) * 128;
    l[o] = e0 * wp[lane] + e1 * wp[lane + 64];
  }
#pragma unroll
  for (int s = 32; s >= 1; s >>= 1)
#pragma unroll
    for (int o = 0; o < 10; ++o) l[o] += __shfl_xor(l[o], s, 64);
#pragma unroll
  for (int o = 0; o < 10; ++o) l[o] += cbias[e * 10 + o];
  float m = l[0];
#pragma unroll
  for (int o = 1; o < 10; ++o) m = fmaxf(m, l[o]);
  float p[10], sum = 0.f;
#pragma unroll
  for (int o = 0; o < 10; ++o) { p[o] = expf(l[o] - m); sum += p[o]; }
  float inv = 1.f / sum, ent = 0.f;
#pragma unroll
  for (int o = 0; o < 10; ++o) { float pp = p[o] * inv; ent -= pp * logf(pp + 1e-12f); }
  if (lane == 0) {
    conf[b * 16 + e] = -ent;
#pragma unroll
    for (int o = 0; o < 10; ++o) logits_e[((size_t)b * 16 + e) * 10 + o] = l[o];
  }
}

__global__ void gate23_k(const float* __restrict__ g1, const float* __restrict__ w2,
                         const float* __restrict__ b2, const float* __restrict__ w3,
                         const float* __restrict__ b3, float* __restrict__ scores)
{
  int wv   = (blockIdx.x * 256 + threadIdx.x) >> 6;
  int lane = threadIdx.x & 63;
  int b = wv >> 4, e = wv & 15;
  float gv = g1[((size_t)e * 512 + b) * 64 + lane];
  const float* w3p = w3 + e * 32;
  float sc = 0.f;
#pragma unroll
  for (int o = 0; o < 32; ++o) {
    float t = gv * w2[((size_t)e * 32 + o) * 64 + lane];
#pragma unroll
    for (int s = 32; s >= 1; s >>= 1) t += __shfl_xor(t, s, 64);
    float g2v = fmaxf(t + b2[e * 32 + o], 0.f);
    sc = fmaf(g2v, w3p[o], sc);
  }
  if (lane == 0) scores[b * 16 + e] = sc + b3[e];
}

__global__ void routing_k(const float* __restrict__ scores, const float* __restrict__ conf,
                          const float* __restrict__ logits_e, float* __restrict__ out)
{
  __shared__ int t2[512];
  __shared__ int chs[512];
  const int tid = threadIdx.x;

  if (tid < 512) {
    int b = tid;
    float v0 = -3.4e38f, v1 = -3.4e38f;
    int i0 = 0, i1 = 0;
#pragma unroll
    for (int e = 0; e < 16; ++e) {
      float s = scores[b * 16 + e];
      float c = conf[b * 16 + e];
      float v = 0.7f * s + 0.3f * c - 0.125f;
      out[5120 + b * 16 + e] = v;
      if (v > v0) { v1 = v0; i1 = i0; v0 = v; i0 = e; }
      else if (v > v1) { v1 = v; i1 = e; }
    }
    t2[b] = i0 | (i1 << 8);
  }
  __syncthreads();

  if (tid < 64) {
    int lane = tid;
    int cnt = 0;
    int pk[8];
#pragma unroll
    for (int k = 0; k < 8; ++k) pk[k] = t2[k * 64 + lane];
#pragma unroll 1
    for (int k = 0; k < 8; ++k) {
      for (int j = 0; j < 64; ++j) {
        int pair = __shfl(pk[k], j, 64);
        int i0 = pair & 0xff, i1 = (pair >> 8) & 0xff;
        int c0 = __shfl(cnt, i0, 64);
        int c1 = __shfl(cnt, i1, 64);
        int ch = (c0 < 64) ? i0 : ((c1 < 64) ? i1 : ((c0 <= c1) ? i0 : i1));
        cnt += (lane == ch) ? 1 : 0;
        if (lane == 0) chs[k * 64 + j] = ch;
      }
    }
  }
  __syncthreads();

  if (tid < 512) {
    int b = tid;
    int ch = chs[b];
#pragma unroll
    for (int e = 0; e < 16; ++e)
      out[13312 + b * 16 + e] = (e == ch) ? 1.0f : 0.0f;
#pragma unroll
    for (int o = 0; o < 10; ++o)
      out[b * 10 + o] = logits_e[((size_t)b * 16 + ch) * 10 + o];
  }
}

// ============================================================================
extern "C" void kernel_launch(void* const* d_in, const int* in_sizes, int n_in,
                              void* d_out, int out_size, void* d_ws, size_t ws_size,
                              hipStream_t stream) {
  (void)in_sizes; (void)n_in; (void)out_size; (void)ws_size;

  const float* x = (const float*)d_in[0];
  const float *cw[6], *cbv[6], *bsv[6], *bbv[6];
  for (int i = 0; i < 6; ++i) {
    cw[i]  = (const float*)d_in[1 + 4 * i];
    cbv[i] = (const float*)d_in[2 + 4 * i];
    bsv[i] = (const float*)d_in[3 + 4 * i];
    bbv[i] = (const float*)d_in[4 + 4 * i];
  }
  const float* gate_w1  = (const float*)d_in[25];
  const float* gate_b1  = (const float*)d_in[26];
  const float* gate_g1  = (const float*)d_in[27];
  const float* gate_bb1 = (const float*)d_in[28];
  const float* gate_w2  = (const float*)d_in[29];
  const float* gate_b2  = (const float*)d_in[30];
  const float* gate_w3  = (const float*)d_in[31];
  const float* gate_b3  = (const float*)d_in[32];
  const float* exp_w1   = (const float*)d_in[33];
  const float* exp_b1   = (const float*)d_in[34];
  const float* exp_g1   = (const float*)d_in[35];
  const float* exp_bb1  = (const float*)d_in[36];
  const float* exp_w2   = (const float*)d_in[37];
  const float* exp_b2   = (const float*)d_in[38];
  const float* exp_g2   = (const float*)d_in[39];
  const float* exp_bb2  = (const float*)d_in[40];
  const float* exp_w3   = (const float*)d_in[41];
  const float* exp_b3   = (const float*)d_in[42];
  const float* cls_w    = (const float*)d_in[43];
  const float* cls_b    = (const float*)d_in[44];

  char* wsb = (char*)d_ws;
  // byte offsets (total 192,142,080 B == proven R3 footprint)
  const size_t off_wt1t = 0;                       // 6912 B
  const size_t off_whi  = 6912;                    // 2,285,568 B
  const size_t off_wlo  = 2292480;                 // 2,285,568 B
  const size_t off_Phi  = 4578048;                 // 67,108,864 B
  const size_t off_Plo  = 71686912;                // 67,108,864 B
  const size_t off_Qhi  = 138795776;               // 16,777,216 B
  const size_t off_Qlo  = 155572992;               // 16,777,216 B
  const size_t off_feats= 172350208;               // 524,288 B
  const size_t off_h1   = 172874496;               // 8,388,608 B
  const size_t off_h2   = 181263104;               // 4,194,304 B
  const size_t off_emb  = 185457408;               // 4,194,304 B
  const size_t off_g1   = 189651712;               // 2,097,152 B
  const size_t off_lg   = 191748864;               // 327,680 B
  const size_t off_conf = 192076544;               // 32,768 B
  const size_t off_sc   = 192109312;               // 32,768 B

  float* wt1t = (float*)(wsb + off_wt1t);
  h16* whi = (h16*)(wsb + off_whi);
  h16* wlo = (h16*)(wsb + off_wlo);
  h16* Phi = (h16*)(wsb + off_Phi);
  h16* Plo = (h16*)(wsb + off_Plo);
  h16* Qhi = (h16*)(wsb + off_Qhi);
  h16* Qlo = (h16*)(wsb + off_Qlo);
  float* feats = (float*)(wsb + off_feats);
  float* h1 = (float*)(wsb + off_h1);
  float* h2 = (float*)(wsb + off_h2);
  float* emb = (float*)(wsb + off_emb);
  float* g1 = (float*)(wsb + off_g1);
  float* lg = (float*)(wsb + off_lg);
  float* conf = (float*)(wsb + off_conf);
  float* sc = (float*)(wsb + off_sc);

  // per-layer element offsets into whi/wlo ([tap][co][ci], fp16)
  const size_t wo2 = 0;        // 9*64*64    = 36864
  const size_t wo3 = 36864;    // 9*128*64   = 73728
  const size_t wo4 = 110592;   // 9*128*128  = 147456
  const size_t wo5 = 258048;   // 9*256*128  = 294912
  const size_t wo6 = 552960;   // 9*256*256  = 589824

  auto cdiv = [](int a, int b) { return (a + b - 1) / b; };

  // ---- weight prep ----
  wt_transpose_k<<<cdiv(27 * 64, 256), 256, 0, stream>>>(cw[0], wt1t, 27, 64);
  wsplit_k<<<cdiv(9 * 64 * 64, 256),   256, 0, stream>>>(cw[1], whi + wo2, wlo + wo2, 64, 64);
  wsplit_k<<<cdiv(9 * 128 * 64, 256),  256, 0, stream>>>(cw[2], whi + wo3, wlo + wo3, 64, 128);
  wsplit_k<<<cdiv(9 * 128 * 128, 256), 256, 0, stream>>>(cw[3], whi + wo4, wlo + wo4, 128, 128);
  wsplit_k<<<cdiv(9 * 256 * 128, 256), 256, 0, stream>>>(cw[4], whi + wo5, wlo + wo5, 128, 256);
  wsplit_k<<<cdiv(9 * 256 * 256, 256), 256, 0, stream>>>(cw[5], whi + wo6, wlo + wo6, 256, 256);

  // ---- trunk ----
  conv1_k<<<512, 256, 0, stream>>>(x, wt1t, cbv[0], bsv[0], bbv[0], Phi, Plo);
  // <H, W, CIN, COUT, MT, MW, NW, POOL>
  conv_mfma<32, 32, 64, 64, 4, 4, 1, 1><<<dim3(512, 2, 1), 256, 0, stream>>>(
      Phi, Plo, whi + wo2, wlo + wo2, cbv[1], bsv[1], bbv[1], Qhi, Qlo, nullptr);
  conv_mfma<16, 16, 64, 128, 4, 2, 2, 0><<<dim3(512, 1, 1), 256, 0, stream>>>(
      Qhi, Qlo, whi + wo3, wlo + wo3, cbv[2], bsv[2], bbv[2], Phi, Plo, nullptr);
  conv_mfma<16, 16, 128, 128, 4, 2, 2, 1><<<dim3(512, 1, 1), 256, 0, stream>>>(
      Phi, Plo, whi + wo4, wlo + wo4, cbv[3], bsv[3], bbv[3], Qhi, Qlo, nullptr);
  conv_mfma<8, 8, 128, 256, 2, 2, 2, 0><<<dim3(256, 1, 2), 256, 0, stream>>>(
      Qhi, Qlo, whi + wo5, wlo + wo5, cbv[4], bsv[4], bbv[4], Phi, Plo, nullptr);
  conv_mfma<8, 8, 256, 256, 2, 2, 2, 2><<<dim3(256, 1, 2), 256, 0, stream>>>(
      Phi, Plo, whi + wo6, wlo + wo6, cbv[5], bsv[5], bbv[5], nullptr, nullptr, feats);

  // ---- experts ----
  gemm_head<256, 256, 1, 1><<<dim3(8, 16), 256, 0, stream>>>(
      feats, (size_t)0, exp_w1, exp_b1, exp_g1, exp_bb1, h1);
  gemm_head<128, 256, 1, 1><<<dim3(8, 16), 256, 0, stream>>>(
      h1, (size_t)512 * 256, exp_w2, exp_b2, exp_g2, exp_bb2, h2);
  gemm_head<128, 128, 0, 0><<<dim3(8, 16), 256, 0, stream>>>(
      h2, (size_t)512 * 128, exp_w3, exp_b3, nullptr, nullptr, emb);
  cls_softmax_k<<<2048, 256, 0, stream>>>(emb, cls_w, cls_b, lg, conf);

  // ---- gates ----
  gemm_head<64, 256, 1, 1><<<dim3(8, 16), 256, 0, stream>>>(
      feats, (size_t)0, gate_w1, gate_b1, gate_g1, gate_bb1, g1);
  gate23_k<<<2048, 256, 0, stream>>>(g1, gate_w2, gate_b2, gate_w3, gate_b3, sc);

  // ---- routing + outputs ----
  routing_k<<<1, 512, 0, stream>>>(sc, conf, lg, (float*)d_out);
}

// Round 5
// 1078.421 us; speedup vs baseline: 41.7234x; 1.7795x over previous
//
#include <hip/hip_runtime.h>

// ============================================================================
// ImprovedMoE R5: R4 (fp16x2-split MFMA conv trunk) + channel-blocked
// activation/weight layouts for coalesced A/B fragment loads.
//   Activations: [img][ck][y][x][c16]  (ck = ci/16, c16 = ci%16), hi/lo planes
//   Weights:     [tap][ck][co][c16]                             , hi/lo planes
// A-frag load: consecutive lanes (pixels) 32B apart -> 2KB/wave contiguous.
// B-frag load: consecutive lanes (co)     32B apart -> coalesced.
// Tap shift = +/-16-elt offset within plane (L1-resident re-reads).
// Heads/routing unchanged (verified). Workspace == 192,142,080 B.
// ============================================================================

typedef _Float16 h16;
typedef _Float16 half8 __attribute__((ext_vector_type(8)));
typedef float f32x16 __attribute__((ext_vector_type(16)));

__device__ __forceinline__ void split2f(float x, h16& hh, h16& ll) {
  h16 a = (h16)x;
  hh = a;
  ll = (h16)(x - (float)a);
}

// ---- conv1 weight transpose: w[co][ci*9+tap] -> wt[ci*9+tap][co] ----
__global__ void wt_transpose_k(const float* __restrict__ w, float* __restrict__ wt,
                               int CI9, int CO) {
  int n = CI9 * CO;
  int idx = blockIdx.x * 256 + threadIdx.x;
  if (idx < n) {
    int co = idx % CO;
    int r  = idx / CO;
    wt[idx] = w[(size_t)co * CI9 + r];
  }
}

// ---- split conv weights: w[co][ci][tap] -> wh/wl[tap][ck][co][c16] ----
__global__ void wsplit_k(const float* __restrict__ w, h16* __restrict__ wh,
                         h16* __restrict__ wl, int CIN, int COUT) {
  int total = 9 * COUT * CIN;
  int idx = blockIdx.x * 256 + threadIdx.x;
  if (idx >= total) return;
  // idx == ((tap*KC + ck)*COUT + co)*16 + c16
  int c16 = idx & 15;
  int t   = idx >> 4;
  int co  = t % COUT;
  int tc  = t / COUT;
  int KC  = CIN >> 4;
  int ck  = tc % KC;
  int tap = tc / KC;
  int ci  = ck * 16 + c16;
  float v = w[((size_t)co * CIN + ci) * 9 + tap];
  h16 hh, ll;
  split2f(v, hh, ll);
  wh[idx] = hh;
  wl[idx] = ll;
}

// ---- conv1: 3->64, 32x32, fp32 vector; outputs blocked hi/lo fp16 planes ----
__global__ __launch_bounds__(256) void conv1_k(
    const float* __restrict__ x, const float* __restrict__ wt,
    const float* __restrict__ cb, const float* __restrict__ bns,
    const float* __restrict__ bnb, h16* __restrict__ oh, h16* __restrict__ ol)
{
  __shared__ float sx[3 * 34 * 34];
  const int tid = threadIdx.x;
  const int img = blockIdx.x;
  for (int idx = tid; idx < 3 * 34 * 34; idx += 256) {
    int xx = idx % 34;
    int t  = idx / 34;
    int rr = t % 34;
    int c  = t / 34;
    int gr = rr - 1, gx = xx - 1;
    float v = 0.f;
    if (gr >= 0 && gr < 32 && gx >= 0 && gx < 32)
      v = x[((size_t)(img * 3 + c) * 32 + gr) * 32 + gx];
    sx[(c * 34 + rr) * 34 + xx] = v;
  }
  __syncthreads();
#pragma unroll 1
  for (int k = 0; k < 4; ++k) {
    int px = k * 256 + tid;
    int yy = px >> 5, xx = px & 31;
    float in27[27];
#pragma unroll
    for (int c = 0; c < 3; ++c)
#pragma unroll
      for (int dy = 0; dy < 3; ++dy)
#pragma unroll
        for (int dx = 0; dx < 3; ++dx)
          in27[c * 9 + dy * 3 + dx] = sx[(c * 34 + yy + dy) * 34 + xx + dx];
#pragma unroll 1
    for (int cbk = 0; cbk < 4; ++cbk) {           // 4 channel-blocks of 16
      h16 hb[16], lb[16];
#pragma unroll
      for (int j = 0; j < 16; ++j) {
        int co = cbk * 16 + j;
        float acc = 0.f;
#pragma unroll
        for (int t = 0; t < 27; ++t) acc = fmaf(in27[t], wt[t * 64 + co], acc);
        float s = bns[co];
        float yv = fmaxf(fmaf(acc + cb[co], s, bnb[co]), 0.f);
        split2f(yv, hb[j], lb[j]);
      }
      size_t o = ((size_t)(img * 4 + cbk) * 1024 + px) * 16;
      *(half8*)&oh[o]     = *(half8*)&hb[0];
      *(half8*)&oh[o + 8] = *(half8*)&hb[8];
      *(half8*)&ol[o]     = *(half8*)&lb[0];
      *(half8*)&ol[o + 8] = *(half8*)&lb[8];
    }
  }
}

// ---------------------------------------------------------------------------
// MFMA conv: 3x3 SAME, fp16x2-split, tap-decomposed implicit GEMM.
// Blocked layouts (see header). Wave tile: (MT*32) px x 64 co.
// POOL: 0 none, 1 maxpool2x2 (RPT==1 cross-tile / RPT==2 intra-reg),
//       2 global avg -> feats.
// ---------------------------------------------------------------------------
template<int H, int W, int CIN, int COUT, int MT, int MW, int NW, int POOL>
__global__ __launch_bounds__(256, 2) void conv_mfma(
    const h16* __restrict__ Ah, const h16* __restrict__ Al,
    const h16* __restrict__ Wh, const h16* __restrict__ Wl,
    const float* __restrict__ cb, const float* __restrict__ bns,
    const float* __restrict__ bnb,
    h16* __restrict__ Oh, h16* __restrict__ Ol, float* __restrict__ feats)
{
  constexpr int TPI  = (H * W) / 32;
  constexpr int RPT  = 32 / W;
  constexpr int IPB  = (MT * MW * 32 >= H * W) ? (MT * MW * 32) / (H * W) : 1;
  constexpr int KC   = CIN / 16;
  constexpr int HW   = H * W;
  constexpr int KCO  = COUT / 16;
  constexpr int LOGW = (W == 32) ? 5 : (W == 16) ? 4 : 3;

  const int tid  = threadIdx.x;
  const int lane = tid & 63;
  const int wave = tid >> 6;
  const int half = lane >> 5;
  const int col  = lane & 31;
  const int wm   = wave % MW;
  const int wn   = wave / MW;
  const int co0  = blockIdx.z * (NW * 64) + wn * 64;

  int aoff[MT], ty[MT], tx[MT], img_t[MT], rw0[MT];
#pragma unroll
  for (int t = 0; t < MT; ++t) {
    int gt   = blockIdx.y * (MT * MW) + wm * MT + t;
    int img  = blockIdx.x * IPB + gt / TPI;
    int row0 = (gt % TPI) * RPT;
    int y = row0 + (col >> LOGW);
    int x = col & (W - 1);
    img_t[t] = img; rw0[t] = row0; ty[t] = y; tx[t] = x;
    aoff[t] = ((img * KC) * HW + y * W + x) * 16 + half * 8;   // ck=0 base
  }

  half8 hz;
#pragma unroll
  for (int i = 0; i < 8; ++i) hz[i] = (h16)0.f;

  f32x16 acc[MT][2];
#pragma unroll
  for (int t = 0; t < MT; ++t)
#pragma unroll
    for (int n = 0; n < 2; ++n)
#pragma unroll
      for (int i = 0; i < 16; ++i) acc[t][n][i] = 0.f;

#pragma unroll 1
  for (int ck = 0; ck < KC; ++ck) {
    const int ckoA = ck * (HW * 16);
#pragma unroll
    for (int tap = 0; tap < 9; ++tap) {
      const int dy = tap / 3 - 1, dx = tap % 3 - 1;
      const int ashift = (dy * W + dx) * 16;
      half8 bh[2], bl[2];
#pragma unroll
      for (int n = 0; n < 2; ++n) {
        int bi = ((tap * KC + ck) * COUT + co0 + n * 32 + col) * 16 + half * 8;
        bh[n] = *(const half8*)(Wh + bi);
        bl[n] = *(const half8*)(Wl + bi);
      }
      half8 ah[MT], al[MT];
#pragma unroll
      for (int t = 0; t < MT; ++t) {
        bool v = ((unsigned)(ty[t] + dy) < (unsigned)H) &&
                 ((unsigned)(tx[t] + dx) < (unsigned)W);
        int ai = v ? (aoff[t] + ckoA + ashift) : 0;
        half8 h = *(const half8*)(Ah + ai);
        half8 l = *(const half8*)(Al + ai);
        ah[t] = v ? h : hz;
        al[t] = v ? l : hz;
      }
#pragma unroll
      for (int t = 0; t < MT; ++t)
#pragma unroll
        for (int n = 0; n < 2; ++n) {
          acc[t][n] = __builtin_amdgcn_mfma_f32_32x32x16_f16(ah[t], bh[n], acc[t][n], 0, 0, 0);
          acc[t][n] = __builtin_amdgcn_mfma_f32_32x32x16_f16(al[t], bh[n], acc[t][n], 0, 0, 0);
          acc[t][n] = __builtin_amdgcn_mfma_f32_32x32x16_f16(ah[t], bl[n], acc[t][n], 0, 0, 0);
        }
    }
  }

  // ---- epilogue: y = acc*s + (cb*s+bb), relu, pool, split-store (blocked) ----
  // C/D layout: col(co)=lane&31, row(px)=(reg&3)+4*half+8*(reg>>2)
#pragma unroll
  for (int n = 0; n < 2; ++n) {
    const int co = co0 + n * 32 + col;
    const float es = bns[co];
    const float eb = fmaf(cb[co], es, bnb[co]);
    const int cko = co >> 4, c16 = co & 15;

    if constexpr (POOL == 0) {
#pragma unroll
      for (int t = 0; t < MT; ++t) {
#pragma unroll
        for (int r = 0; r < 16; ++r) {
          float v = fmaxf(fmaf(acc[t][n][r], es, eb), 0.f);
          int m = (r & 3) + 4 * half + 8 * (r >> 2);
          int y = rw0[t] + (m >> LOGW);
          int x = m & (W - 1);
          size_t oi = ((size_t)(img_t[t] * KCO + cko) * HW + y * W + x) * 16 + c16;
          h16 hh, ll; split2f(v, hh, ll);
          Oh[oi] = hh; Ol[oi] = ll;
        }
      }
    } else if constexpr (POOL == 1 && RPT == 1) {   // conv2: y-pair across tiles
      constexpr int HWq = (H / 2) * (W / 2);
#pragma unroll
      for (int tp = 0; tp < MT / 2; ++tp) {
        const int t0 = 2 * tp, t1 = 2 * tp + 1;
        const int yq = rw0[t0] >> 1;
#pragma unroll
        for (int r = 0; r < 16; r += 2) {
          float v00 = fmaxf(fmaf(acc[t0][n][r],     es, eb), 0.f);
          float v01 = fmaxf(fmaf(acc[t0][n][r + 1], es, eb), 0.f);
          float v10 = fmaxf(fmaf(acc[t1][n][r],     es, eb), 0.f);
          float v11 = fmaxf(fmaf(acc[t1][n][r + 1], es, eb), 0.f);
          float mv = fmaxf(fmaxf(v00, v01), fmaxf(v10, v11));
          int xq = ((r & 3) >> 1) + 2 * half + 4 * (r >> 2);
          size_t oi = ((size_t)(img_t[t0] * KCO + cko) * HWq + yq * (W / 2) + xq) * 16 + c16;
          h16 hh, ll; split2f(mv, hh, ll);
          Oh[oi] = hh; Ol[oi] = ll;
        }
      }
    } else if constexpr (POOL == 1) {               // conv4 (RPT==2): intra-reg
      constexpr int HWq = (H / 2) * (W / 2);
#pragma unroll
      for (int t = 0; t < MT; ++t) {
        const int yq = rw0[t] >> 1;
#pragma unroll
        for (int r = 0; r < 8; r += 2) {
          float v00 = fmaxf(fmaf(acc[t][n][r],     es, eb), 0.f);
          float v01 = fmaxf(fmaf(acc[t][n][r + 1], es, eb), 0.f);
          float v10 = fmaxf(fmaf(acc[t][n][r + 8], es, eb), 0.f);
          float v11 = fmaxf(fmaf(acc[t][n][r + 9], es, eb), 0.f);
          float mv = fmaxf(fmaxf(v00, v01), fmaxf(v10, v11));
          int xq = ((r & 3) >> 1) + 2 * half + 4 * (r >> 2);
          size_t oi = ((size_t)(img_t[t] * KCO + cko) * HWq + yq * (W / 2) + xq) * 16 + c16;
          h16 hh, ll; split2f(mv, hh, ll);
          Oh[oi] = hh; Ol[oi] = ll;
        }
      }
    } else {                                        // POOL==2: avg -> feats
      float s = 0.f;
#pragma unroll
      for (int t = 0; t < MT; ++t)
#pragma unroll
        for (int r = 0; r < 16; ++r)
          s += fmaxf(fmaf(acc[t][n][r], es, eb), 0.f);
      s += __shfl_xor(s, 32, 64);
      if (half == 0) feats[(size_t)img_t[0] * 256 + co] = s * (1.f / 64.f);
    }
  }
}

// ---------------------------------------------------------------------------
// Batched head GEMM (R1, verified).
// ---------------------------------------------------------------------------
template<int O, int K, int LN, int RELU>
__global__ __launch_bounds__(256, 4) void gemm_head(
    const float* __restrict__ A, size_t aStrideE,
    const float* __restrict__ Wm, const float* __restrict__ bias,
    const float* __restrict__ g, const float* __restrict__ bb,
    float* __restrict__ out)
{
  constexpr int KC  = (O >= 256) ? 32 : 64;
  constexpr int WST = O + 4;
  constexpr int TO  = O / 16;
  __shared__ float sA[KC * 68];
  __shared__ float sW[KC * WST];
  __shared__ float mArr[64], rArr[64];

  const int tid  = threadIdx.x;
  const int lane = tid & 63;
  const int wave = tid >> 6;
  const int e    = blockIdx.y;
  const int b0g  = blockIdx.x * 64;
  const int bl   = (lane & 15) * 4;
  const int ol   = wave * (O / 4) + (lane >> 4) * TO;

  const float* Ae = A + (size_t)e * aStrideE;
  const float* We = Wm + (size_t)e * O * K;

  float acc[4][TO];
#pragma unroll
  for (int i = 0; i < 4; ++i)
#pragma unroll
    for (int j = 0; j < TO; ++j) acc[i][j] = 0.f;

  for (int k0 = 0; k0 < K; k0 += KC) {
    for (int idx = tid; idx < 64 * KC; idx += 256) {
      int kk = idx % KC, bb_ = idx / KC;
      sA[kk * 68 + bb_] = Ae[(size_t)(b0g + bb_) * K + k0 + kk];
    }
    for (int idx = tid; idx < O * KC; idx += 256) {
      int kk = idx % KC, oo = idx / KC;
      sW[kk * WST + oo] = We[(size_t)oo * K + k0 + kk];
    }
    __syncthreads();
#pragma unroll 4
    for (int kk = 0; kk < KC; ++kk) {
      float4 av = *(const float4*)&sA[kk * 68 + bl];
      float a4[4] = {av.x, av.y, av.z, av.w};
#pragma unroll
      for (int j4 = 0; j4 < TO; j4 += 4) {
        float4 wv = *(const float4*)&sW[kk * WST + ol + j4];
        float w4[4] = {wv.x, wv.y, wv.z, wv.w};
#pragma unroll
        for (int i = 0; i < 4; ++i)
#pragma unroll
          for (int jj = 0; jj < 4; ++jj)
            acc[i][j4 + jj] = fmaf(a4[i], w4[jj], acc[i][j4 + jj]);
      }
    }
    __syncthreads();
  }

  const float* bi = bias + (size_t)e * O;
#pragma unroll
  for (int i = 0; i < 4; ++i)
#pragma unroll
    for (int j = 0; j < TO; ++j) acc[i][j] += bi[ol + j];

  if constexpr (LN) {
    float* redS = sA;
    float* redQ = sA + 1024;
    const int grp = wave * 4 + (lane >> 4);
#pragma unroll
    for (int i = 0; i < 4; ++i) {
      float s = 0.f, q = 0.f;
#pragma unroll
      for (int j = 0; j < TO; ++j) { s += acc[i][j]; q += acc[i][j] * acc[i][j]; }
      redS[(bl + i) * 16 + grp] = s;
      redQ[(bl + i) * 16 + grp] = q;
    }
    __syncthreads();
    if (tid < 64) {
      float s = 0.f, q = 0.f;
#pragma unroll
      for (int gi = 0; gi < 16; ++gi) { s += redS[tid * 16 + gi]; q += redQ[tid * 16 + gi]; }
      float mean = s * (1.f / O);
      float var  = q * (1.f / O) - mean * mean;
      mArr[tid] = mean;
      rArr[tid] = rsqrtf(var + 1e-5f);
    }
    __syncthreads();
    const float* gp  = g + (size_t)e * O;
    const float* bbp = bb + (size_t)e * O;
#pragma unroll
    for (int i = 0; i < 4; ++i) {
      float mean = mArr[bl + i], rstd = rArr[bl + i];
#pragma unroll
      for (int j = 0; j < TO; ++j)
        acc[i][j] = (acc[i][j] - mean) * rstd * gp[ol + j] + bbp[ol + j];
    }
  }
  if constexpr (RELU) {
#pragma unroll
    for (int i = 0; i < 4; ++i)
#pragma unroll
      for (int j = 0; j < TO; ++j) acc[i][j] = fmaxf(acc[i][j], 0.f);
  }
#pragma unroll
  for (int i = 0; i < 4; ++i) {
    float* op = out + ((size_t)e * 512 + b0g + bl + i) * O + ol;
#pragma unroll
    for (int j4 = 0; j4 < TO; j4 += 4)
      *(float4*)(op + j4) = make_float4(acc[i][j4], acc[i][j4 + 1], acc[i][j4 + 2], acc[i][j4 + 3]);
  }
}

__global__ void cls_softmax_k(const float* __restrict__ embeds,
                              const float* __restrict__ cw,
                              const float* __restrict__ cbias,
                              float* __restrict__ logits_e,
                              float* __restrict__ conf)
{
  int wv   = (blockIdx.x * 256 + threadIdx.x) >> 6;
  int lane = threadIdx.x & 63;
  int b = wv >> 4, e = wv & 15;
  const float* ep = embeds + ((size_t)e * 512 + b) * 128;
  float e0 = ep[lane], e1 = ep[lane + 64];
  float l[10];
#pragma unroll
  for (int o = 0; o < 10; ++o) {
    const float* wp = cw + ((size_t)e * 10 + o) * 128;
    l[o] = e0 * wp[lane] + e1 * wp[lane + 64];
  }
#pragma unroll
  for (int s = 32; s >= 1; s >>= 1)
#pragma unroll
    for (int o = 0; o < 10; ++o) l[o] += __shfl_xor(l[o], s, 64);
#pragma unroll
  for (int o = 0; o < 10; ++o) l[o] += cbias[e * 10 + o];
  float m = l[0];
#pragma unroll
  for (int o = 1; o < 10; ++o) m = fmaxf(m, l[o]);
  float p[10], sum = 0.f;
#pragma unroll
  for (int o = 0; o < 10; ++o) { p[o] = expf(l[o] - m); sum += p[o]; }
  float inv = 1.f / sum, ent = 0.f;
#pragma unroll
  for (int o = 0; o < 10; ++o) { float pp = p[o] * inv; ent -= pp * logf(pp + 1e-12f); }
  if (lane == 0) {
    conf[b * 16 + e] = -ent;
#pragma unroll
    for (int o = 0; o < 10; ++o) logits_e[((size_t)b * 16 + e) * 10 + o] = l[o];
  }
}

__global__ void gate23_k(const float* __restrict__ g1, const float* __restrict__ w2,
                         const float* __restrict__ b2, const float* __restrict__ w3,
                         const float* __restrict__ b3, float* __restrict__ scores)
{
  int wv   = (blockIdx.x * 256 + threadIdx.x) >> 6;
  int lane = threadIdx.x & 63;
  int b = wv >> 4, e = wv & 15;
  float gv = g1[((size_t)e * 512 + b) * 64 + lane];
  const float* w3p = w3 + e * 32;
  float sc = 0.f;
#pragma unroll
  for (int o = 0; o < 32; ++o) {
    float t = gv * w2[((size_t)e * 32 + o) * 64 + lane];
#pragma unroll
    for (int s = 32; s >= 1; s >>= 1) t += __shfl_xor(t, s, 64);
    float g2v = fmaxf(t + b2[e * 32 + o], 0.f);
    sc = fmaf(g2v, w3p[o], sc);
  }
  if (lane == 0) scores[b * 16 + e] = sc + b3[e];
}

__global__ void routing_k(const float* __restrict__ scores, const float* __restrict__ conf,
                          const float* __restrict__ logits_e, float* __restrict__ out)
{
  __shared__ int t2[512];
  __shared__ int chs[512];
  const int tid = threadIdx.x;

  if (tid < 512) {
    int b = tid;
    float v0 = -3.4e38f, v1 = -3.4e38f;
    int i0 = 0, i1 = 0;
#pragma unroll
    for (int e = 0; e < 16; ++e) {
      float s = scores[b * 16 + e];
      float c = conf[b * 16 + e];
      float v = 0.7f * s + 0.3f * c - 0.125f;
      out[5120 + b * 16 + e] = v;
      if (v > v0) { v1 = v0; i1 = i0; v0 = v; i0 = e; }
      else if (v > v1) { v1 = v; i1 = e; }
    }
    t2[b] = i0 | (i1 << 8);
  }
  __syncthreads();

  if (tid < 64) {
    int lane = tid;
    int cnt = 0;
    int pk[8];
#pragma unroll
    for (int k = 0; k < 8; ++k) pk[k] = t2[k * 64 + lane];
#pragma unroll 1
    for (int k = 0; k < 8; ++k) {
      for (int j = 0; j < 64; ++j) {
        int pair = __shfl(pk[k], j, 64);
        int i0 = pair & 0xff, i1 = (pair >> 8) & 0xff;
        int c0 = __shfl(cnt, i0, 64);
        int c1 = __shfl(cnt, i1, 64);
        int ch = (c0 < 64) ? i0 : ((c1 < 64) ? i1 : ((c0 <= c1) ? i0 : i1));
        cnt += (lane == ch) ? 1 : 0;
        if (lane == 0) chs[k * 64 + j] = ch;
      }
    }
  }
  __syncthreads();

  if (tid < 512) {
    int b = tid;
    int ch = chs[b];
#pragma unroll
    for (int e = 0; e < 16; ++e)
      out[13312 + b * 16 + e] = (e == ch) ? 1.0f : 0.0f;
#pragma unroll
    for (int o = 0; o < 10; ++o)
      out[b * 10 + o] = logits_e[((size_t)b * 16 + ch) * 10 + o];
  }
}

// ============================================================================
extern "C" void kernel_launch(void* const* d_in, const int* in_sizes, int n_in,
                              void* d_out, int out_size, void* d_ws, size_t ws_size,
                              hipStream_t stream) {
  (void)in_sizes; (void)n_in; (void)out_size; (void)ws_size;

  const float* x = (const float*)d_in[0];
  const float *cw[6], *cbv[6], *bsv[6], *bbv[6];
  for (int i = 0; i < 6; ++i) {
    cw[i]  = (const float*)d_in[1 + 4 * i];
    cbv[i] = (const float*)d_in[2 + 4 * i];
    bsv[i] = (const float*)d_in[3 + 4 * i];
    bbv[i] = (const float*)d_in[4 + 4 * i];
  }
  const float* gate_w1  = (const float*)d_in[25];
  const float* gate_b1  = (const float*)d_in[26];
  const float* gate_g1  = (const float*)d_in[27];
  const float* gate_bb1 = (const float*)d_in[28];
  const float* gate_w2  = (const float*)d_in[29];
  const float* gate_b2  = (const float*)d_in[30];
  const float* gate_w3  = (const float*)d_in[31];
  const float* gate_b3  = (const float*)d_in[32];
  const float* exp_w1   = (const float*)d_in[33];
  const float* exp_b1   = (const float*)d_in[34];
  const float* exp_g1   = (const float*)d_in[35];
  const float* exp_bb1  = (const float*)d_in[36];
  const float* exp_w2   = (const float*)d_in[37];
  const float* exp_b2   = (const float*)d_in[38];
  const float* exp_g2   = (const float*)d_in[39];
  const float* exp_bb2  = (const float*)d_in[40];
  const float* exp_w3   = (const float*)d_in[41];
  const float* exp_b3   = (const float*)d_in[42];
  const float* cls_w    = (const float*)d_in[43];
  const float* cls_b    = (const float*)d_in[44];

  char* wsb = (char*)d_ws;
  const size_t off_wt1t = 0;
  const size_t off_whi  = 6912;
  const size_t off_wlo  = 2292480;
  const size_t off_Phi  = 4578048;
  const size_t off_Plo  = 71686912;
  const size_t off_Qhi  = 138795776;
  const size_t off_Qlo  = 155572992;
  const size_t off_feats= 172350208;
  const size_t off_h1   = 172874496;
  const size_t off_h2   = 181263104;
  const size_t off_emb  = 185457408;
  const size_t off_g1   = 189651712;
  const size_t off_lg   = 191748864;
  const size_t off_conf = 192076544;
  const size_t off_sc   = 192109312;

  float* wt1t = (float*)(wsb + off_wt1t);
  h16* whi = (h16*)(wsb + off_whi);
  h16* wlo = (h16*)(wsb + off_wlo);
  h16* Phi = (h16*)(wsb + off_Phi);
  h16* Plo = (h16*)(wsb + off_Plo);
  h16* Qhi = (h16*)(wsb + off_Qhi);
  h16* Qlo = (h16*)(wsb + off_Qlo);
  float* feats = (float*)(wsb + off_feats);
  float* h1 = (float*)(wsb + off_h1);
  float* h2 = (float*)(wsb + off_h2);
  float* emb = (float*)(wsb + off_emb);
  float* g1 = (float*)(wsb + off_g1);
  float* lg = (float*)(wsb + off_lg);
  float* conf = (float*)(wsb + off_conf);
  float* sc = (float*)(wsb + off_sc);

  const size_t wo2 = 0;
  const size_t wo3 = 36864;
  const size_t wo4 = 110592;
  const size_t wo5 = 258048;
  const size_t wo6 = 552960;

  auto cdiv = [](int a, int b) { return (a + b - 1) / b; };

  // ---- weight prep ----
  wt_transpose_k<<<cdiv(27 * 64, 256), 256, 0, stream>>>(cw[0], wt1t, 27, 64);
  wsplit_k<<<cdiv(9 * 64 * 64, 256),   256, 0, stream>>>(cw[1], whi + wo2, wlo + wo2, 64, 64);
  wsplit_k<<<cdiv(9 * 128 * 64, 256),  256, 0, stream>>>(cw[2], whi + wo3, wlo + wo3, 64, 128);
  wsplit_k<<<cdiv(9 * 128 * 128, 256), 256, 0, stream>>>(cw[3], whi + wo4, wlo + wo4, 128, 128);
  wsplit_k<<<cdiv(9 * 256 * 128, 256), 256, 0, stream>>>(cw[4], whi + wo5, wlo + wo5, 128, 256);
  wsplit_k<<<cdiv(9 * 256 * 256, 256), 256, 0, stream>>>(cw[5], whi + wo6, wlo + wo6, 256, 256);

  // ---- trunk ----
  conv1_k<<<512, 256, 0, stream>>>(x, wt1t, cbv[0], bsv[0], bbv[0], Phi, Plo);
  // <H, W, CIN, COUT, MT, MW, NW, POOL>
  conv_mfma<32, 32, 64, 64, 4, 4, 1, 1><<<dim3(512, 2, 1), 256, 0, stream>>>(
      Phi, Plo, whi + wo2, wlo + wo2, cbv[1], bsv[1], bbv[1], Qhi, Qlo, nullptr);
  conv_mfma<16, 16, 64, 128, 4, 2, 2, 0><<<dim3(512, 1, 1), 256, 0, stream>>>(
      Qhi, Qlo, whi + wo3, wlo + wo3, cbv[2], bsv[2], bbv[2], Phi, Plo, nullptr);
  conv_mfma<16, 16, 128, 128, 4, 2, 2, 1><<<dim3(512, 1, 1), 256, 0, stream>>>(
      Phi, Plo, whi + wo4, wlo + wo4, cbv[3], bsv[3], bbv[3], Qhi, Qlo, nullptr);
  conv_mfma<8, 8, 128, 256, 2, 2, 2, 0><<<dim3(256, 1, 2), 256, 0, stream>>>(
      Qhi, Qlo, whi + wo5, wlo + wo5, cbv[4], bsv[4], bbv[4], Phi, Plo, nullptr);
  conv_mfma<8, 8, 256, 256, 2, 2, 2, 2><<<dim3(256, 1, 2), 256, 0, stream>>>(
      Phi, Plo, whi + wo6, wlo + wo6, cbv[5], bsv[5], bbv[5], nullptr, nullptr, feats);

  // ---- experts ----
  gemm_head<256, 256, 1, 1><<<dim3(8, 16), 256, 0, stream>>>(
      feats, (size_t)0, exp_w1, exp_b1, exp_g1, exp_bb1, h1);
  gemm_head<128, 256, 1, 1><<<dim3(8, 16), 256, 0, stream>>>(
      h1, (size_t)512 * 256, exp_w2, exp_b2, exp_g2, exp_bb2, h2);
  gemm_head<128, 128, 0, 0><<<dim3(8, 16), 256, 0, stream>>>(
      h2, (size_t)512 * 128, exp_w3, exp_b3, nullptr, nullptr, emb);
  cls_softmax_k<<<2048, 256, 0, stream>>>(emb, cls_w, cls_b, lg, conf);

  // ---- gates ----
  gemm_head<64, 256, 1, 1><<<dim3(8, 16), 256, 0, stream>>>(
      feats, (size_t)0, gate_w1, gate_b1, gate_g1, gate_bb1, g1);
  gate23_k<<<2048, 256, 0, stream>>>(g1, gate_w2, gate_b2, gate_w3, gate_b3, sc);

  // ---- routing + outputs ----
  routing_k<<<1, 512, 0, stream>>>(sc, conf, lg, (float*)d_out);
}

// Round 6
// 1009.138 us; speedup vs baseline: 44.5879x; 1.0687x over previous
//
#include <hip/hip_runtime.h>

// ============================================================================
// ImprovedMoE R6 = R5 + (a) zero-pad sentinel before each activation plane
// (invalid lanes load zeros from the pad -> no per-element cndmask),
// (b) ck-loop unroll 2 on conv3..6 (cross-ck load/MFMA pipelining),
// (c) ws re-layout with head buffers overlapped into dead Q region.
// Layouts: act [img][ck][y][x][c16] (+16-elt zero pad prefix), wt [tap][ck][co][c16].
// ============================================================================

typedef _Float16 h16;
typedef _Float16 half8 __attribute__((ext_vector_type(8)));
typedef float f32x16 __attribute__((ext_vector_type(16)));

__device__ __forceinline__ void split2f(float x, h16& hh, h16& ll) {
  h16 a = (h16)x;
  hh = a;
  ll = (h16)(x - (float)a);
}

__global__ void zero_pads_k(h16* p0, h16* p1, h16* p2, h16* p3) {
  int t = threadIdx.x;
  if (t < 16) { p0[t] = (h16)0.f; p1[t] = (h16)0.f; p2[t] = (h16)0.f; p3[t] = (h16)0.f; }
}

// ---- conv1 weight transpose: w[co][ci*9+tap] -> wt[ci*9+tap][co] ----
__global__ void wt_transpose_k(const float* __restrict__ w, float* __restrict__ wt,
                               int CI9, int CO) {
  int n = CI9 * CO;
  int idx = blockIdx.x * 256 + threadIdx.x;
  if (idx < n) {
    int co = idx % CO;
    int r  = idx / CO;
    wt[idx] = w[(size_t)co * CI9 + r];
  }
}

// ---- split conv weights: w[co][ci][tap] -> wh/wl[tap][ck][co][c16] ----
__global__ void wsplit_k(const float* __restrict__ w, h16* __restrict__ wh,
                         h16* __restrict__ wl, int CIN, int COUT) {
  int total = 9 * COUT * CIN;
  int idx = blockIdx.x * 256 + threadIdx.x;
  if (idx >= total) return;
  int c16 = idx & 15;
  int t   = idx >> 4;
  int co  = t % COUT;
  int tc  = t / COUT;
  int KC  = CIN >> 4;
  int ck  = tc % KC;
  int tap = tc / KC;
  int ci  = ck * 16 + c16;
  float v = w[((size_t)co * CIN + ci) * 9 + tap];
  h16 hh, ll;
  split2f(v, hh, ll);
  wh[idx] = hh;
  wl[idx] = ll;
}

// ---- conv1: 3->64, 32x32, fp32 vector; outputs blocked hi/lo planes (+16) ----
__global__ __launch_bounds__(256) void conv1_k(
    const float* __restrict__ x, const float* __restrict__ wt,
    const float* __restrict__ cb, const float* __restrict__ bns,
    const float* __restrict__ bnb, h16* __restrict__ oh, h16* __restrict__ ol)
{
  __shared__ float sx[3 * 34 * 34];
  const int tid = threadIdx.x;
  const int img = blockIdx.x;
  for (int idx = tid; idx < 3 * 34 * 34; idx += 256) {
    int xx = idx % 34;
    int t  = idx / 34;
    int rr = t % 34;
    int c  = t / 34;
    int gr = rr - 1, gx = xx - 1;
    float v = 0.f;
    if (gr >= 0 && gr < 32 && gx >= 0 && gx < 32)
      v = x[((size_t)(img * 3 + c) * 32 + gr) * 32 + gx];
    sx[(c * 34 + rr) * 34 + xx] = v;
  }
  __syncthreads();
#pragma unroll 1
  for (int k = 0; k < 4; ++k) {
    int px = k * 256 + tid;
    int yy = px >> 5, xx = px & 31;
    float in27[27];
#pragma unroll
    for (int c = 0; c < 3; ++c)
#pragma unroll
      for (int dy = 0; dy < 3; ++dy)
#pragma unroll
        for (int dx = 0; dx < 3; ++dx)
          in27[c * 9 + dy * 3 + dx] = sx[(c * 34 + yy + dy) * 34 + xx + dx];
#pragma unroll 1
    for (int cbk = 0; cbk < 4; ++cbk) {
      h16 hb[16], lb[16];
#pragma unroll
      for (int j = 0; j < 16; ++j) {
        int co = cbk * 16 + j;
        float acc = 0.f;
#pragma unroll
        for (int t = 0; t < 27; ++t) acc = fmaf(in27[t], wt[t * 64 + co], acc);
        float s = bns[co];
        float yv = fmaxf(fmaf(acc + cb[co], s, bnb[co]), 0.f);
        split2f(yv, hb[j], lb[j]);
      }
      size_t o = 16 + ((size_t)(img * 4 + cbk) * 1024 + px) * 16;
      *(half8*)&oh[o]     = *(half8*)&hb[0];
      *(half8*)&oh[o + 8] = *(half8*)&hb[8];
      *(half8*)&ol[o]     = *(half8*)&lb[0];
      *(half8*)&ol[o + 8] = *(half8*)&lb[8];
    }
  }
}

// ---------------------------------------------------------------------------
// MFMA conv: 3x3 SAME, fp16x2-split, tap-decomposed implicit GEMM.
// Invalid (halo) lanes load from the 16-elt zero pad at plane start.
// KUNR: ck-loop unroll factor (cross-ck pipelining).
// ---------------------------------------------------------------------------
#define CONV_CK_STEP                                                          \
    {                                                                         \
      const int ckoA = ck * (HW * 16);                                        \
      _Pragma("unroll")                                                       \
      for (int tap = 0; tap < 9; ++tap) {                                     \
        const int dy = tap / 3 - 1, dx = tap % 3 - 1;                         \
        const int ashift = (dy * W + dx) * 16;                                \
        half8 bh[2], bl[2];                                                   \
        _Pragma("unroll")                                                     \
        for (int n = 0; n < 2; ++n) {                                         \
          int bi = ((tap * KC + ck) * COUT + co0 + n * 32 + col) * 16 + half * 8; \
          bh[n] = *(const half8*)(Wh + bi);                                   \
          bl[n] = *(const half8*)(Wl + bi);                                   \
        }                                                                     \
        half8 ah[MT], al[MT];                                                 \
        _Pragma("unroll")                                                     \
        for (int t = 0; t < MT; ++t) {                                        \
          bool v = ((unsigned)(ty[t] + dy) < (unsigned)H) &&                  \
                   ((unsigned)(tx[t] + dx) < (unsigned)W);                    \
          int ai = v ? (aoff[t] + ckoA + ashift) : (half * 8);                \
          ah[t] = *(const half8*)(Ah + ai);                                   \
          al[t] = *(const half8*)(Al + ai);                                   \
        }                                                                     \
        _Pragma("unroll")                                                     \
        for (int t = 0; t < MT; ++t)                                          \
          _Pragma("unroll")                                                   \
          for (int n = 0; n < 2; ++n) {                                       \
            acc[t][n] = __builtin_amdgcn_mfma_f32_32x32x16_f16(ah[t], bh[n], acc[t][n], 0, 0, 0); \
            acc[t][n] = __builtin_amdgcn_mfma_f32_32x32x16_f16(al[t], bh[n], acc[t][n], 0, 0, 0); \
            acc[t][n] = __builtin_amdgcn_mfma_f32_32x32x16_f16(ah[t], bl[n], acc[t][n], 0, 0, 0); \
          }                                                                   \
      }                                                                       \
    }

template<int H, int W, int CIN, int COUT, int MT, int MW, int NW, int POOL, int KUNR>
__global__ __launch_bounds__(256, 2) void conv_mfma(
    const h16* __restrict__ Ah, const h16* __restrict__ Al,
    const h16* __restrict__ Wh, const h16* __restrict__ Wl,
    const float* __restrict__ cb, const float* __restrict__ bns,
    const float* __restrict__ bnb,
    h16* __restrict__ Oh, h16* __restrict__ Ol, float* __restrict__ feats)
{
  constexpr int TPI  = (H * W) / 32;
  constexpr int RPT  = 32 / W;
  constexpr int IPB  = (MT * MW * 32 >= H * W) ? (MT * MW * 32) / (H * W) : 1;
  constexpr int KC   = CIN / 16;
  constexpr int HW   = H * W;
  constexpr int KCO  = COUT / 16;
  constexpr int LOGW = (W == 32) ? 5 : (W == 16) ? 4 : 3;

  const int tid  = threadIdx.x;
  const int lane = tid & 63;
  const int wave = tid >> 6;
  const int half = lane >> 5;
  const int col  = lane & 31;
  const int wm   = wave % MW;
  const int wn   = wave / MW;
  const int co0  = blockIdx.z * (NW * 64) + wn * 64;

  int aoff[MT], ty[MT], tx[MT], img_t[MT], rw0[MT];
#pragma unroll
  for (int t = 0; t < MT; ++t) {
    int gt   = blockIdx.y * (MT * MW) + wm * MT + t;
    int img  = blockIdx.x * IPB + gt / TPI;
    int row0 = (gt % TPI) * RPT;
    int y = row0 + (col >> LOGW);
    int x = col & (W - 1);
    img_t[t] = img; rw0[t] = row0; ty[t] = y; tx[t] = x;
    aoff[t] = 16 + ((img * KC) * HW + y * W + x) * 16 + half * 8;
  }

  f32x16 acc[MT][2];
#pragma unroll
  for (int t = 0; t < MT; ++t)
#pragma unroll
    for (int n = 0; n < 2; ++n)
#pragma unroll
      for (int i = 0; i < 16; ++i) acc[t][n][i] = 0.f;

  if constexpr (KUNR == 2) {
#pragma unroll 2
    for (int ck = 0; ck < KC; ++ck) CONV_CK_STEP
  } else {
#pragma unroll 1
    for (int ck = 0; ck < KC; ++ck) CONV_CK_STEP
  }

  // ---- epilogue: y = acc*s + (cb*s+bb), relu, pool, split-store (blocked+16) ----
#pragma unroll
  for (int n = 0; n < 2; ++n) {
    const int co = co0 + n * 32 + col;
    const float es = bns[co];
    const float eb = fmaf(cb[co], es, bnb[co]);
    const int cko = co >> 4, c16 = co & 15;

    if constexpr (POOL == 0) {
#pragma unroll
      for (int t = 0; t < MT; ++t) {
#pragma unroll
        for (int r = 0; r < 16; ++r) {
          float v = fmaxf(fmaf(acc[t][n][r], es, eb), 0.f);
          int m = (r & 3) + 4 * half + 8 * (r >> 2);
          int y = rw0[t] + (m >> LOGW);
          int x = m & (W - 1);
          size_t oi = 16 + ((size_t)(img_t[t] * KCO + cko) * HW + y * W + x) * 16 + c16;
          h16 hh, ll; split2f(v, hh, ll);
          Oh[oi] = hh; Ol[oi] = ll;
        }
      }
    } else if constexpr (POOL == 1 && RPT == 1) {   // conv2: y-pair across tiles
      constexpr int HWq = (H / 2) * (W / 2);
#pragma unroll
      for (int tp = 0; tp < MT / 2; ++tp) {
        const int t0 = 2 * tp, t1 = 2 * tp + 1;
        const int yq = rw0[t0] >> 1;
#pragma unroll
        for (int r = 0; r < 16; r += 2) {
          float v00 = fmaxf(fmaf(acc[t0][n][r],     es, eb), 0.f);
          float v01 = fmaxf(fmaf(acc[t0][n][r + 1], es, eb), 0.f);
          float v10 = fmaxf(fmaf(acc[t1][n][r],     es, eb), 0.f);
          float v11 = fmaxf(fmaf(acc[t1][n][r + 1], es, eb), 0.f);
          float mv = fmaxf(fmaxf(v00, v01), fmaxf(v10, v11));
          int xq = ((r & 3) >> 1) + 2 * half + 4 * (r >> 2);
          size_t oi = 16 + ((size_t)(img_t[t0] * KCO + cko) * HWq + yq * (W / 2) + xq) * 16 + c16;
          h16 hh, ll; split2f(mv, hh, ll);
          Oh[oi] = hh; Ol[oi] = ll;
        }
      }
    } else if constexpr (POOL == 1) {               // conv4 (RPT==2): intra-reg
      constexpr int HWq = (H / 2) * (W / 2);
#pragma unroll
      for (int t = 0; t < MT; ++t) {
        const int yq = rw0[t] >> 1;
#pragma unroll
        for (int r = 0; r < 8; r += 2) {
          float v00 = fmaxf(fmaf(acc[t][n][r],     es, eb), 0.f);
          float v01 = fmaxf(fmaf(acc[t][n][r + 1], es, eb), 0.f);
          float v10 = fmaxf(fmaf(acc[t][n][r + 8], es, eb), 0.f);
          float v11 = fmaxf(fmaf(acc[t][n][r + 9], es, eb), 0.f);
          float mv = fmaxf(fmaxf(v00, v01), fmaxf(v10, v11));
          int xq = ((r & 3) >> 1) + 2 * half + 4 * (r >> 2);
          size_t oi = 16 + ((size_t)(img_t[t] * KCO + cko) * HWq + yq * (W / 2) + xq) * 16 + c16;
          h16 hh, ll; split2f(mv, hh, ll);
          Oh[oi] = hh; Ol[oi] = ll;
        }
      }
    } else {                                        // POOL==2: avg -> feats
      float s = 0.f;
#pragma unroll
      for (int t = 0; t < MT; ++t)
#pragma unroll
        for (int r = 0; r < 16; ++r)
          s += fmaxf(fmaf(acc[t][n][r], es, eb), 0.f);
      s += __shfl_xor(s, 32, 64);
      if (half == 0) feats[(size_t)img_t[0] * 256 + co] = s * (1.f / 64.f);
    }
  }
}

// ---------------------------------------------------------------------------
// Batched head GEMM (R1, verified).
// ---------------------------------------------------------------------------
template<int O, int K, int LN, int RELU>
__global__ __launch_bounds__(256, 4) void gemm_head(
    const float* __restrict__ A, size_t aStrideE,
    const float* __restrict__ Wm, const float* __restrict__ bias,
    const float* __restrict__ g, const float* __restrict__ bb,
    float* __restrict__ out)
{
  constexpr int KC  = (O >= 256) ? 32 : 64;
  constexpr int WST = O + 4;
  constexpr int TO  = O / 16;
  __shared__ float sA[KC * 68];
  __shared__ float sW[KC * WST];
  __shared__ float mArr[64], rArr[64];

  const int tid  = threadIdx.x;
  const int lane = tid & 63;
  const int wave = tid >> 6;
  const int e    = blockIdx.y;
  const int b0g  = blockIdx.x * 64;
  const int bl   = (lane & 15) * 4;
  const int ol   = wave * (O / 4) + (lane >> 4) * TO;

  const float* Ae = A + (size_t)e * aStrideE;
  const float* We = Wm + (size_t)e * O * K;

  float acc[4][TO];
#pragma unroll
  for (int i = 0; i < 4; ++i)
#pragma unroll
    for (int j = 0; j < TO; ++j) acc[i][j] = 0.f;

  for (int k0 = 0; k0 < K; k0 += KC) {
    for (int idx = tid; idx < 64 * KC; idx += 256) {
      int kk = idx % KC, bb_ = idx / KC;
      sA[kk * 68 + bb_] = Ae[(size_t)(b0g + bb_) * K + k0 + kk];
    }
    for (int idx = tid; idx < O * KC; idx += 256) {
      int kk = idx % KC, oo = idx / KC;
      sW[kk * WST + oo] = We[(size_t)oo * K + k0 + kk];
    }
    __syncthreads();
#pragma unroll 4
    for (int kk = 0; kk < KC; ++kk) {
      float4 av = *(const float4*)&sA[kk * 68 + bl];
      float a4[4] = {av.x, av.y, av.z, av.w};
#pragma unroll
      for (int j4 = 0; j4 < TO; j4 += 4) {
        float4 wv = *(const float4*)&sW[kk * WST + ol + j4];
        float w4[4] = {wv.x, wv.y, wv.z, wv.w};
#pragma unroll
        for (int i = 0; i < 4; ++i)
#pragma unroll
          for (int jj = 0; jj < 4; ++jj)
            acc[i][j4 + jj] = fmaf(a4[i], w4[jj], acc[i][j4 + jj]);
      }
    }
    __syncthreads();
  }

  const float* bi = bias + (size_t)e * O;
#pragma unroll
  for (int i = 0; i < 4; ++i)
#pragma unroll
    for (int j = 0; j < TO; ++j) acc[i][j] += bi[ol + j];

  if constexpr (LN) {
    float* redS = sA;
    float* redQ = sA + 1024;
    const int grp = wave * 4 + (lane >> 4);
#pragma unroll
    for (int i = 0; i < 4; ++i) {
      float s = 0.f, q = 0.f;
#pragma unroll
      for (int j = 0; j < TO; ++j) { s += acc[i][j]; q += acc[i][j] * acc[i][j]; }
      redS[(bl + i) * 16 + grp] = s;
      redQ[(bl + i) * 16 + grp] = q;
    }
    __syncthreads();
    if (tid < 64) {
      float s = 0.f, q = 0.f;
#pragma unroll
      for (int gi = 0; gi < 16; ++gi) { s += redS[tid * 16 + gi]; q += redQ[tid * 16 + gi]; }
      float mean = s * (1.f / O);
      float var  = q * (1.f / O) - mean * mean;
      mArr[tid] = mean;
      rArr[tid] = rsqrtf(var + 1e-5f);
    }
    __syncthreads();
    const float* gp  = g + (size_t)e * O;
    const float* bbp = bb + (size_t)e * O;
#pragma unroll
    for (int i = 0; i < 4; ++i) {
      float mean = mArr[bl + i], rstd = rArr[bl + i];
#pragma unroll
      for (int j = 0; j < TO; ++j)
        acc[i][j] = (acc[i][j] - mean) * rstd * gp[ol + j] + bbp[ol + j];
    }
  }
  if constexpr (RELU) {
#pragma unroll
    for (int i = 0; i < 4; ++i)
#pragma unroll
      for (int j = 0; j < TO; ++j) acc[i][j] = fmaxf(acc[i][j], 0.f);
  }
#pragma unroll
  for (int i = 0; i < 4; ++i) {
    float* op = out + ((size_t)e * 512 + b0g + bl + i) * O + ol;
#pragma unroll
    for (int j4 = 0; j4 < TO; j4 += 4)
      *(float4*)(op + j4) = make_float4(acc[i][j4], acc[i][j4 + 1], acc[i][j4 + 2], acc[i][j4 + 3]);
  }
}

__global__ void cls_softmax_k(const float* __restrict__ embeds,
                              const float* __restrict__ cw,
                              const float* __restrict__ cbias,
                              float* __restrict__ logits_e,
                              float* __restrict__ conf)
{
  int wv   = (blockIdx.x * 256 + threadIdx.x) >> 6;
  int lane = threadIdx.x & 63;
  int b = wv >> 4, e = wv & 15;
  const float* ep = embeds + ((size_t)e * 512 + b) * 128;
  float e0 = ep[lane], e1 = ep[lane + 64];
  float l[10];
#pragma unroll
  for (int o = 0; o < 10; ++o) {
    const float* wp = cw + ((size_t)e * 10 + o) * 128;
    l[o] = e0 * wp[lane] + e1 * wp[lane + 64];
  }
#pragma unroll
  for (int s = 32; s >= 1; s >>= 1)
#pragma unroll
    for (int o = 0; o < 10; ++o) l[o] += __shfl_xor(l[o], s, 64);
#pragma unroll
  for (int o = 0; o < 10; ++o) l[o] += cbias[e * 10 + o];
  float m = l[0];
#pragma unroll
  for (int o = 1; o < 10; ++o) m = fmaxf(m, l[o]);
  float p[10], sum = 0.f;
#pragma unroll
  for (int o = 0; o < 10; ++o) { p[o] = expf(l[o] - m); sum += p[o]; }
  float inv = 1.f / sum, ent = 0.f;
#pragma unroll
  for (int o = 0; o < 10; ++o) { float pp = p[o] * inv; ent -= pp * logf(pp + 1e-12f); }
  if (lane == 0) {
    conf[b * 16 + e] = -ent;
#pragma unroll
    for (int o = 0; o < 10; ++o) logits_e[((size_t)b * 16 + e) * 10 + o] = l[o];
  }
}

__global__ void gate23_k(const float* __restrict__ g1, const float* __restrict__ w2,
                         const float* __restrict__ b2, const float* __restrict__ w3,
                         const float* __restrict__ b3, float* __restrict__ scores)
{
  int wv   = (blockIdx.x * 256 + threadIdx.x) >> 6;
  int lane = threadIdx.x & 63;
  int b = wv >> 4, e = wv & 15;
  float gv = g1[((size_t)e * 512 + b) * 64 + lane];
  const float* w3p = w3 + e * 32;
  float sc = 0.f;
#pragma unroll
  for (int o = 0; o < 32; ++o) {
    float t = gv * w2[((size_t)e * 32 + o) * 64 + lane];
#pragma unroll
    for (int s = 32; s >= 1; s >>= 1) t += __shfl_xor(t, s, 64);
    float g2v = fmaxf(t + b2[e * 32 + o], 0.f);
    sc = fmaf(g2v, w3p[o], sc);
  }
  if (lane == 0) scores[b * 16 + e] = sc + b3[e];
}

__global__ void routing_k(const float* __restrict__ scores, const float* __restrict__ conf,
                          const float* __restrict__ logits_e, float* __restrict__ out)
{
  __shared__ int t2[512];
  __shared__ int chs[512];
  const int tid = threadIdx.x;

  if (tid < 512) {
    int b = tid;
    float v0 = -3.4e38f, v1 = -3.4e38f;
    int i0 = 0, i1 = 0;
#pragma unroll
    for (int e = 0; e < 16; ++e) {
      float s = scores[b * 16 + e];
      float c = conf[b * 16 + e];
      float v = 0.7f * s + 0.3f * c - 0.125f;
      out[5120 + b * 16 + e] = v;
      if (v > v0) { v1 = v0; i1 = i0; v0 = v; i0 = e; }
      else if (v > v1) { v1 = v; i1 = e; }
    }
    t2[b] = i0 | (i1 << 8);
  }
  __syncthreads();

  if (tid < 64) {
    int lane = tid;
    int cnt = 0;
    int pk[8];
#pragma unroll
    for (int k = 0; k < 8; ++k) pk[k] = t2[k * 64 + lane];
#pragma unroll 1
    for (int k = 0; k < 8; ++k) {
      for (int j = 0; j < 64; ++j) {
        int pair = __shfl(pk[k], j, 64);
        int i0 = pair & 0xff, i1 = (pair >> 8) & 0xff;
        int c0 = __shfl(cnt, i0, 64);
        int c1 = __shfl(cnt, i1, 64);
        int ch = (c0 < 64) ? i0 : ((c1 < 64) ? i1 : ((c0 <= c1) ? i0 : i1));
        cnt += (lane == ch) ? 1 : 0;
        if (lane == 0) chs[k * 64 + j] = ch;
      }
    }
  }
  __syncthreads();

  if (tid < 512) {
    int b = tid;
    int ch = chs[b];
#pragma unroll
    for (int e = 0; e < 16; ++e)
      out[13312 + b * 16 + e] = (e == ch) ? 1.0f : 0.0f;
#pragma unroll
    for (int o = 0; o < 10; ++o)
      out[b * 10 + o] = logits_e[((size_t)b * 16 + ch) * 10 + o];
  }
}

// ============================================================================
extern "C" void kernel_launch(void* const* d_in, const int* in_sizes, int n_in,
                              void* d_out, int out_size, void* d_ws, size_t ws_size,
                              hipStream_t stream) {
  (void)in_sizes; (void)n_in; (void)out_size; (void)ws_size;

  const float* x = (const float*)d_in[0];
  const float *cw[6], *cbv[6], *bsv[6], *bbv[6];
  for (int i = 0; i < 6; ++i) {
    cw[i]  = (const float*)d_in[1 + 4 * i];
    cbv[i] = (const float*)d_in[2 + 4 * i];
    bsv[i] = (const float*)d_in[3 + 4 * i];
    bbv[i] = (const float*)d_in[4 + 4 * i];
  }
  const float* gate_w1  = (const float*)d_in[25];
  const float* gate_b1  = (const float*)d_in[26];
  const float* gate_g1  = (const float*)d_in[27];
  const float* gate_bb1 = (const float*)d_in[28];
  const float* gate_w2  = (const float*)d_in[29];
  const float* gate_b2  = (const float*)d_in[30];
  const float* gate_w3  = (const float*)d_in[31];
  const float* gate_b3  = (const float*)d_in[32];
  const float* exp_w1   = (const float*)d_in[33];
  const float* exp_b1   = (const float*)d_in[34];
  const float* exp_g1   = (const float*)d_in[35];
  const float* exp_bb1  = (const float*)d_in[36];
  const float* exp_w2   = (const float*)d_in[37];
  const float* exp_b2   = (const float*)d_in[38];
  const float* exp_g2   = (const float*)d_in[39];
  const float* exp_bb2  = (const float*)d_in[40];
  const float* exp_w3   = (const float*)d_in[41];
  const float* exp_b3   = (const float*)d_in[42];
  const float* cls_w    = (const float*)d_in[43];
  const float* cls_b    = (const float*)d_in[44];

  char* wsb = (char*)d_ws;
  // Planes carry a 256B pad region; data starts at element 16 from the pointer.
  const size_t off_wt1t = 0;                  // 6,912
  const size_t off_whi  = 6912;               // 2,285,568
  const size_t off_wlo  = 2292480;            // 2,285,568 -> 4,578,048
  const size_t off_Phi  = 4578048;            // 256 + 67,108,864
  const size_t off_Plo  = 71687168;           // 256 + 67,108,864
  const size_t off_Qhi  = 138796288;          // 256 + 16,777,216
  const size_t off_Qlo  = 155573760;          // 256 + 16,777,216 -> 172,351,232
  const size_t off_feats= 172351232;          // 524,288 -> 172,875,520 (high water)
  // Head buffers overlap the Q region (dead after conv5):
  const size_t off_h1   = 138796288 + 512;    // 8,388,608
  const size_t off_h2   = off_h1 + 8388608;   // 4,194,304
  const size_t off_emb  = off_h2 + 4194304;   // 4,194,304
  const size_t off_g1   = off_emb + 4194304;  // 2,097,152
  const size_t off_lg   = off_g1 + 2097152;   // 327,680
  const size_t off_conf = off_lg + 327680;    // 32,768
  const size_t off_sc   = off_conf + 32768;   // 32,768

  float* wt1t = (float*)(wsb + off_wt1t);
  h16* whi = (h16*)(wsb + off_whi);
  h16* wlo = (h16*)(wsb + off_wlo);
  h16* Phi = (h16*)(wsb + off_Phi);
  h16* Plo = (h16*)(wsb + off_Plo);
  h16* Qhi = (h16*)(wsb + off_Qhi);
  h16* Qlo = (h16*)(wsb + off_Qlo);
  float* feats = (float*)(wsb + off_feats);
  float* h1 = (float*)(wsb + off_h1);
  float* h2 = (float*)(wsb + off_h2);
  float* emb = (float*)(wsb + off_emb);
  float* g1 = (float*)(wsb + off_g1);
  float* lg = (float*)(wsb + off_lg);
  float* conf = (float*)(wsb + off_conf);
  float* sc = (float*)(wsb + off_sc);

  const size_t wo2 = 0;
  const size_t wo3 = 36864;
  const size_t wo4 = 110592;
  const size_t wo5 = 258048;
  const size_t wo6 = 552960;

  auto cdiv = [](int a, int b) { return (a + b - 1) / b; };

  // ---- pads + weight prep ----
  zero_pads_k<<<1, 64, 0, stream>>>(Phi, Plo, Qhi, Qlo);
  wt_transpose_k<<<cdiv(27 * 64, 256), 256, 0, stream>>>(cw[0], wt1t, 27, 64);
  wsplit_k<<<cdiv(9 * 64 * 64, 256),   256, 0, stream>>>(cw[1], whi + wo2, wlo + wo2, 64, 64);
  wsplit_k<<<cdiv(9 * 128 * 64, 256),  256, 0, stream>>>(cw[2], whi + wo3, wlo + wo3, 64, 128);
  wsplit_k<<<cdiv(9 * 128 * 128, 256), 256, 0, stream>>>(cw[3], whi + wo4, wlo + wo4, 128, 128);
  wsplit_k<<<cdiv(9 * 256 * 128, 256), 256, 0, stream>>>(cw[4], whi + wo5, wlo + wo5, 128, 256);
  wsplit_k<<<cdiv(9 * 256 * 256, 256), 256, 0, stream>>>(cw[5], whi + wo6, wlo + wo6, 256, 256);

  // ---- trunk ----
  conv1_k<<<512, 256, 0, stream>>>(x, wt1t, cbv[0], bsv[0], bbv[0], Phi, Plo);
  // <H, W, CIN, COUT, MT, MW, NW, POOL, KUNR>
  conv_mfma<32, 32, 64, 64, 4, 4, 1, 1, 1><<<dim3(512, 2, 1), 256, 0, stream>>>(
      Phi, Plo, whi + wo2, wlo + wo2, cbv[1], bsv[1], bbv[1], Qhi, Qlo, nullptr);
  conv_mfma<16, 16, 64, 128, 4, 2, 2, 0, 2><<<dim3(512, 1, 1), 256, 0, stream>>>(
      Qhi, Qlo, whi + wo3, wlo + wo3, cbv[2], bsv[2], bbv[2], Phi, Plo, nullptr);
  conv_mfma<16, 16, 128, 128, 4, 2, 2, 1, 2><<<dim3(512, 1, 1), 256, 0, stream>>>(
      Phi, Plo, whi + wo4, wlo + wo4, cbv[3], bsv[3], bbv[3], Qhi, Qlo, nullptr);
  conv_mfma<8, 8, 128, 256, 2, 2, 2, 0, 2><<<dim3(256, 1, 2), 256, 0, stream>>>(
      Qhi, Qlo, whi + wo5, wlo + wo5, cbv[4], bsv[4], bbv[4], Phi, Plo, nullptr);
  conv_mfma<8, 8, 256, 256, 2, 2, 2, 2, 2><<<dim3(256, 1, 2), 256, 0, stream>>>(
      Phi, Plo, whi + wo6, wlo + wo6, cbv[5], bsv[5], bbv[5], nullptr, nullptr, feats);

  // ---- experts ----
  gemm_head<256, 256, 1, 1><<<dim3(8, 16), 256, 0, stream>>>(
      feats, (size_t)0, exp_w1, exp_b1, exp_g1, exp_bb1, h1);
  gemm_head<128, 256, 1, 1><<<dim3(8, 16), 256, 0, stream>>>(
      h1, (size_t)512 * 256, exp_w2, exp_b2, exp_g2, exp_bb2, h2);
  gemm_head<128, 128, 0, 0><<<dim3(8, 16), 256, 0, stream>>>(
      h2, (size_t)512 * 128, exp_w3, exp_b3, nullptr, nullptr, emb);
  cls_softmax_k<<<2048, 256, 0, stream>>>(emb, cls_w, cls_b, lg, conf);

  // ---- gates ----
  gemm_head<64, 256, 1, 1><<<dim3(8, 16), 256, 0, stream>>>(
      feats, (size_t)0, gate_w1, gate_b1, gate_g1, gate_bb1, g1);
  gate23_k<<<2048, 256, 0, stream>>>(g1, gate_w2, gate_b2, gate_w3, gate_b3, sc);

  // ---- routing + outputs ----
  routing_k<<<1, 512, 0, stream>>>(sc, conf, lg, (float*)d_out);
}